// Round 2
// baseline (31140.735 us; speedup 1.0000x reference)
//
#include <hip/hip_runtime.h>
#include <math.h>

#define CB 4
#define CT 1024
#define CD 768
#define CH 12
#define CK 64
#define CBH (CB*CH)
#define NB 64

// ---------------- elementwise: token shift + xxx ----------------
__global__ void k_shift(const float* __restrict__ x, const float* __restrict__ tmx,
                        float* __restrict__ dxprev, float* __restrict__ xxx){
    int idx = blockIdx.x*256 + threadIdx.x;
    if (idx >= CB*CT*CD) return;
    int d = idx % CD;
    int bt = idx / CD;
    int t = bt % CT;
    float xc = x[idx];
    float xl = (t > 0)      ? x[idx - CD] : 0.f;
    float xr = (t < CT-1)   ? x[idx + CD] : 0.f;
    float dx = 0.5f*(xl + xr) - xc;
    dxprev[idx] = dx;
    xxx[idx] = xc + dx * tmx[d];
}

// ---------------- generic tiled fp32 GEMM ----------------
// C[M,N] = epilogue(A[M,K] @ B[K,N]); MODE 0 plain, 1 tanh, 2 silu, 3 +bias[n]
template<int MODE>
__global__ void k_gemm(const float* __restrict__ A, const float* __restrict__ Bm,
                       const float* __restrict__ bias, float* __restrict__ C,
                       int M, int N, int Kd){
    __shared__ float As[16][128];
    __shared__ float Bs[16][64];
    int tid = threadIdx.x;
    int m0 = blockIdx.y * 128, n0 = blockIdx.x * 64;
    int tn = (tid & 15) * 4;
    int tm = (tid >> 4) * 8;
    float acc[8][4] = {};
    for (int k0 = 0; k0 < Kd; k0 += 16){
        #pragma unroll
        for (int i = 0; i < 8; i++){
            int e = tid + i*256;
            int r = e >> 4, c = e & 15;
            As[c][r] = A[(size_t)(m0+r)*Kd + k0 + c];
        }
        #pragma unroll
        for (int i = 0; i < 4; i++){
            int e = tid + i*256;
            int r = e >> 6, c = e & 63;
            float bv = 0.f;
            if (n0 + c < N) bv = Bm[(size_t)(k0+r)*N + n0 + c];
            Bs[r][c] = bv;
        }
        __syncthreads();
        #pragma unroll
        for (int kk = 0; kk < 16; kk++){
            float a0[8], b0[4];
            #pragma unroll
            for (int i = 0; i < 8; i++) a0[i] = As[kk][tm+i];
            #pragma unroll
            for (int j = 0; j < 4; j++) b0[j] = Bs[kk][tn+j];
            #pragma unroll
            for (int i = 0; i < 8; i++)
                #pragma unroll
                for (int j = 0; j < 4; j++) acc[i][j] += a0[i]*b0[j];
        }
        __syncthreads();
    }
    #pragma unroll
    for (int i = 0; i < 8; i++)
        #pragma unroll
        for (int j = 0; j < 4; j++){
            int mm = m0 + tm + i, nn = n0 + tn + j;
            if (nn < N){
                float v = acc[i][j];
                if (MODE == 1) v = tanhf(v);
                else if (MODE == 2) v = v / (1.f + expf(-v));
                else if (MODE == 3) v += bias[nn];
                C[(size_t)mm*N + nn] = v;
            }
        }
}

// ---------------- 5-way low-rank mix ----------------
__global__ void k_mix5(const float* __restrict__ x, const float* __restrict__ dxprev,
                       const float* __restrict__ m,
                       const float* __restrict__ tmw, const float* __restrict__ tmk,
                       const float* __restrict__ tmv, const float* __restrict__ tmr,
                       const float* __restrict__ tmg, const float* __restrict__ w2,
                       float* __restrict__ xw, float* __restrict__ xk, float* __restrict__ xv,
                       float* __restrict__ xr, float* __restrict__ xg){
    __shared__ float ms[160];
    int i = blockIdx.y;
    int j = blockIdx.x*256 + threadIdx.x;
    if (threadIdx.x < 160) ms[threadIdx.x] = m[(size_t)i*160 + threadIdx.x];
    __syncthreads();
    float xc = x[(size_t)i*CD + j], dx = dxprev[(size_t)i*CD + j];
    const float* tms[5] = {tmw, tmk, tmv, tmr, tmg};
    float* outs[5] = {xw, xk, xv, xr, xg};
    #pragma unroll
    for (int c = 0; c < 5; c++){
        float s = tms[c][j];
        const float* w2c = w2 + (size_t)c*32*CD + j;
        #pragma unroll
        for (int dm = 0; dm < 32; dm++) s += ms[c*32+dm] * w2c[(size_t)dm*CD];
        outs[c][(size_t)i*CD + j] = xc + dx*s;
    }
}

// ---------------- normalize k, stage v into X (head layout) ----------------
__global__ void k_knvx(const float* __restrict__ k, const float* __restrict__ v,
                       float* __restrict__ kn, float* __restrict__ X){
    int gw = (blockIdx.x*256 + threadIdx.x) >> 6;
    int lane = threadIdx.x & 63;
    if (gw >= CB*CH*CT) return;
    int t = gw % CT; int bh = gw / CT; int h = bh % CH; int b = bh / CH;
    size_t src = ((size_t)(b*CT + t))*CD + h*64 + lane;
    float kv = k[src];
    float ss = kv*kv;
    #pragma unroll
    for (int off = 32; off; off >>= 1) ss += __shfl_xor(ss, off);
    float nrm = fmaxf(sqrtf(ss), 1e-12f);
    size_t dst = ((size_t)bh*CT + t)*64 + lane;
    kn[dst] = kv / nrm;
    X[dst]  = v[src];
}

// ---------------- per-(b,h) decay scan -> rf,kf,rb,kb ----------------
__global__ void __launch_bounds__(1024) k_scan(const float* __restrict__ r, const float* __restrict__ k,
                       const float* __restrict__ w,
                       float* __restrict__ rf, float* __restrict__ kf,
                       float* __restrict__ rb, float* __restrict__ kb){
    __shared__ float s[1024];
    __shared__ float refs[2];
    int bh = blockIdx.x; int h = bh % CH; int b = bh / CH;
    int t = threadIdx.x;
    size_t base_btd = ((size_t)(b*CT + t))*CD + h*64;
    size_t base_hk  = ((size_t)bh*CT + t)*64;
    for (int kk = 0; kk < 64; kk++){
        float wv = -expf(w[base_btd + kk]);
        s[t] = wv;
        __syncthreads();
        for (int off = 1; off < 1024; off <<= 1){
            float add = (t >= off) ? s[t-off] : 0.f;
            __syncthreads();
            s[t] += add;
            __syncthreads();
        }
        float cs = s[t];
        if (t == 512){ refs[0] = cs; refs[1] = wv; }
        __syncthreads();
        float ref_f = refs[0];
        float ref_b = refs[0] - refs[1];
        float csf = fminf(fmaxf(cs - ref_f, -60.f), 60.f);
        float csb = fminf(fmaxf((cs - wv) - ref_b, -60.f), 60.f);
        float rv = r[base_btd + kk], kv = k[base_btd + kk];
        rf[base_hk + kk] = rv * expf(csf);
        kf[base_hk + kk] = kv * expf(-csf);
        rb[base_hk + kk] = rv * expf(-csb);
        kb[base_hk + kk] = kv * expf(csb);
        __syncthreads();
    }
}

// ---------------- P = I + exp(clip(temp * kn knT)) (chunk-local P) ----------------
__global__ void k_gram(const float* __restrict__ kn, const float* __restrict__ lucid_temp,
                       float* __restrict__ P, int bh0){
    __shared__ float tA[64][65];
    __shared__ float tB[64][65];
    int lbh = blockIdx.z; int gbh = bh0 + lbh; int h = gbh % CH;
    int t0 = blockIdx.y*64, s0 = blockIdx.x*64;
    int tid = threadIdx.x;
    #pragma unroll
    for (int i = 0; i < 16; i++){
        int e = tid + i*256; int rr = e >> 6, cc = e & 63;
        tA[rr][cc] = kn[((size_t)gbh*CT + t0+rr)*64 + cc];
        tB[rr][cc] = kn[((size_t)gbh*CT + s0+rr)*64 + cc];
    }
    __syncthreads();
    float tv = lucid_temp[h];
    tv = (tv > 20.f) ? tv : log1pf(expf(tv));
    int ty = (tid >> 4)*4, tx = (tid & 15)*4;
    float acc[4][4] = {};
    #pragma unroll
    for (int kk = 0; kk < 64; kk++){
        float a0[4], b0[4];
        #pragma unroll
        for (int i = 0; i < 4; i++){ a0[i] = tA[ty+i][kk]; b0[i] = tB[tx+i][kk]; }
        #pragma unroll
        for (int i = 0; i < 4; i++)
            #pragma unroll
            for (int j = 0; j < 4; j++) acc[i][j] += a0[i]*b0[j];
    }
    size_t pbase = (size_t)lbh*CT*CT;
    #pragma unroll
    for (int i = 0; i < 4; i++)
        #pragma unroll
        for (int j = 0; j < 4; j++){
            int tt = t0+ty+i, ss = s0+tx+j;
            float gv = fminf(fmaxf(tv*acc[i][j], -20.f), 20.f);
            P[pbase + (size_t)tt*CT + ss] = expf(gv) + ((tt == ss) ? 1.f : 0.f);
        }
}

// ---------------- Cholesky: factor diagonal block + invert (chunk-local) ----------------
__global__ void k_potrf(float* __restrict__ P, float* __restrict__ invL, int jb){
    __shared__ float s[NB][NB+1];
    __shared__ float inv[NB][NB+1];
    int bh = blockIdx.x; int tid = threadIdx.x;
    size_t base = (size_t)bh*CT*CT;
    int j0 = jb*NB;
    #pragma unroll
    for (int i = 0; i < 16; i++){
        int e = tid + i*256; int rr = e >> 6, cc = e & 63;
        int r = (rr >= cc) ? rr : cc, c = (rr >= cc) ? cc : rr;
        s[rr][cc] = P[base + (size_t)(j0+r)*CT + (j0+c)];
    }
    __syncthreads();
    for (int j = 0; j < NB; j++){
        if (tid == 0) s[j][j] = sqrtf(fmaxf(s[j][j], 1e-30f));
        __syncthreads();
        float dj = s[j][j];
        for (int i = j+1+tid; i < NB; i += 256) s[i][j] /= dj;
        __syncthreads();
        int n = NB-1-j;
        for (int e = tid; e < n*n; e += 256){
            int ii = j+1 + e / n, cc2 = j+1 + e % n;
            s[ii][cc2] -= s[ii][j]*s[cc2][j];
        }
        __syncthreads();
    }
    if (tid < NB){
        int c = tid;
        for (int j = 0; j < c; j++) inv[j][c] = 0.f;
        for (int j = c; j < NB; j++){
            float sum = (j == c) ? 1.f : 0.f;
            for (int kk = c; kk < j; kk++) sum -= s[j][kk]*inv[kk][c];
            inv[j][c] = sum / s[j][j];
        }
    }
    __syncthreads();
    float* invp = invL + ((size_t)bh*16 + jb)*NB*NB;
    #pragma unroll
    for (int i = 0; i < 16; i++){
        int e = tid + i*256; int rr = e >> 6, cc = e & 63;
        if (cc <= rr) P[base + (size_t)(j0+rr)*CT + (j0+cc)] = s[rr][cc];
        invp[rr*NB + cc] = inv[rr][cc];
    }
}

// ---------------- TRSM: panel = A21 @ invL11^T (chunk-local) ----------------
__global__ void k_trsm(float* __restrict__ P, const float* __restrict__ invL, int jb){
    __shared__ float a[64][65];
    __shared__ float iv[64][65];
    int bh = blockIdx.y;
    int r0 = (jb+1)*NB + blockIdx.x*64;
    int j0 = jb*NB;
    size_t base = (size_t)bh*CT*CT;
    int tid = threadIdx.x;
    const float* invp = invL + ((size_t)bh*16 + jb)*NB*NB;
    #pragma unroll
    for (int i = 0; i < 16; i++){
        int e = tid + i*256; int rr = e >> 6, cc = e & 63;
        a[rr][cc]  = P[base + (size_t)(r0+rr)*CT + j0 + cc];
        iv[rr][cc] = invp[rr*NB + cc];
    }
    __syncthreads();
    int ty = (tid >> 4)*4, tx = (tid & 15)*4;
    float acc[4][4] = {};
    #pragma unroll
    for (int kk = 0; kk < 64; kk++){
        float a0[4], b0[4];
        #pragma unroll
        for (int i = 0; i < 4; i++){ a0[i] = a[ty+i][kk]; b0[i] = iv[tx+i][kk]; }
        #pragma unroll
        for (int i = 0; i < 4; i++)
            #pragma unroll
            for (int j = 0; j < 4; j++) acc[i][j] += a0[i]*b0[j];
    }
    __syncthreads();
    #pragma unroll
    for (int i = 0; i < 4; i++)
        #pragma unroll
        for (int j = 0; j < 4; j++)
            P[base + (size_t)(r0+ty+i)*CT + j0+tx+j] = acc[i][j];
}

// ---------------- SYRK: A22 -= L21 @ L21^T (lower tiles, chunk-local) ----------------
__global__ void k_syrk(float* __restrict__ P, int jb){
    int ti = blockIdx.y, tj = blockIdx.x;
    if (tj > ti) return;
    int bh = blockIdx.z;
    int off = (jb+1)*NB;
    int r0 = off + ti*64, c0 = off + tj*64;
    int j0 = jb*NB;
    size_t base = (size_t)bh*CT*CT;
    __shared__ float La[64][65], Lb[64][65];
    int tid = threadIdx.x;
    #pragma unroll
    for (int i = 0; i < 16; i++){
        int e = tid + i*256; int rr = e >> 6, cc = e & 63;
        La[rr][cc] = P[base + (size_t)(r0+rr)*CT + j0 + cc];
        Lb[rr][cc] = P[base + (size_t)(c0+rr)*CT + j0 + cc];
    }
    __syncthreads();
    int ty = (tid >> 4)*4, tx = (tid & 15)*4;
    float acc[4][4] = {};
    #pragma unroll
    for (int kk = 0; kk < 64; kk++){
        float a0[4], b0[4];
        #pragma unroll
        for (int i = 0; i < 4; i++){ a0[i] = La[ty+i][kk]; b0[i] = Lb[tx+i][kk]; }
        #pragma unroll
        for (int i = 0; i < 4; i++)
            #pragma unroll
            for (int j = 0; j < 4; j++) acc[i][j] += a0[i]*b0[j];
    }
    #pragma unroll
    for (int i = 0; i < 4; i++)
        #pragma unroll
        for (int j = 0; j < 4; j++)
            P[base + (size_t)(r0+ty+i)*CT + c0+tx+j] -= acc[i][j];
}

// ---------------- forward solve L Y = V (chunk-local P/invL, global X) ----------------
__global__ void k_fwd(const float* __restrict__ P, const float* __restrict__ invL,
                      float* __restrict__ X, int bh0){
    __shared__ float xs[64][65], ys[64][65], Ls[64][65];
    int bh = blockIdx.x, tid = threadIdx.x;
    size_t base = (size_t)bh*CT*CT;
    float* Xb = X + (size_t)(bh0 + bh)*CT*64;
    for (int jb = 0; jb < 16; jb++){
        const float* invp = invL + ((size_t)bh*16 + jb)*4096;
        #pragma unroll
        for (int i = 0; i < 16; i++){
            int e = tid + i*256, rr = e >> 6, cc = e & 63;
            xs[rr][cc] = Xb[(size_t)(jb*64+rr)*64 + cc];
            Ls[rr][cc] = invp[rr*64 + cc];
        }
        __syncthreads();
        #pragma unroll
        for (int i = 0; i < 16; i++){
            int e = tid + i*256, rr = e >> 6, cc = e & 63;
            float sum = 0.f;
            #pragma unroll
            for (int kk = 0; kk < 64; kk++) sum += Ls[rr][kk]*xs[kk][cc];
            ys[rr][cc] = sum;
            Xb[(size_t)(jb*64+rr)*64 + cc] = sum;
        }
        __syncthreads();
        for (int ib = jb+1; ib < 16; ib++){
            #pragma unroll
            for (int i = 0; i < 16; i++){
                int e = tid + i*256, rr = e >> 6, cc = e & 63;
                Ls[rr][cc] = P[base + (size_t)(ib*64+rr)*CT + jb*64 + cc];
            }
            __syncthreads();
            #pragma unroll
            for (int i = 0; i < 16; i++){
                int e = tid + i*256, rr = e >> 6, cc = e & 63;
                float sum = 0.f;
                #pragma unroll
                for (int kk = 0; kk < 64; kk++) sum += Ls[rr][kk]*ys[kk][cc];
                Xb[(size_t)(ib*64+rr)*64 + cc] -= sum;
            }
            __syncthreads();
        }
    }
}

// ---------------- backward solve L^T Z = Y (chunk-local P/invL, global X) ----------------
__global__ void k_bwd(const float* __restrict__ P, const float* __restrict__ invL,
                      float* __restrict__ X, int bh0){
    __shared__ float xs[64][65], ys[64][65], Ls[64][65];
    int bh = blockIdx.x, tid = threadIdx.x;
    size_t base = (size_t)bh*CT*CT;
    float* Xb = X + (size_t)(bh0 + bh)*CT*64;
    for (int jb = 15; jb >= 0; jb--){
        const float* invp = invL + ((size_t)bh*16 + jb)*4096;
        #pragma unroll
        for (int i = 0; i < 16; i++){
            int e = tid + i*256, rr = e >> 6, cc = e & 63;
            xs[rr][cc] = Xb[(size_t)(jb*64+rr)*64 + cc];
            Ls[rr][cc] = invp[rr*64 + cc];
        }
        __syncthreads();
        #pragma unroll
        for (int i = 0; i < 16; i++){
            int e = tid + i*256, rr = e >> 6, cc = e & 63;
            float sum = 0.f;
            #pragma unroll
            for (int kk = 0; kk < 64; kk++) sum += Ls[kk][rr]*xs[kk][cc];
            ys[rr][cc] = sum;
            Xb[(size_t)(jb*64+rr)*64 + cc] = sum;
        }
        __syncthreads();
        for (int ib = 0; ib < jb; ib++){
            #pragma unroll
            for (int i = 0; i < 16; i++){
                int e = tid + i*256, rr = e >> 6, cc = e & 63;
                Ls[rr][cc] = P[base + (size_t)(jb*64+rr)*CT + ib*64 + cc];
            }
            __syncthreads();
            #pragma unroll
            for (int i = 0; i < 16; i++){
                int e = tid + i*256, rr = e >> 6, cc = e & 63;
                float sum = 0.f;
                #pragma unroll
                for (int kk = 0; kk < 64; kk++) sum += Ls[kk][rr]*ys[kk][cc];
                Xb[(size_t)(ib*64+rr)*64 + cc] -= sum;
            }
            __syncthreads();
        }
    }
}

// ---------------- y = (tril(rf kf^T) + triu(rb kb^T,1)) @ Pv ----------------
__global__ void k_apv(const float* __restrict__ rf, const float* __restrict__ kf,
                      const float* __restrict__ rb, const float* __restrict__ kb,
                      const float* __restrict__ X, float* __restrict__ y){
    __shared__ float rs[64][65];
    __shared__ float ks[64][65];
    __shared__ float at[64][65];
    int bh = blockIdx.y;
    int bx = blockIdx.x;
    int t0 = bx * 64;
    int tid = threadIdx.x;
    size_t hb = (size_t)bh*CT*64;
    int tq = tid & 63, kg = tid >> 6;
    float acc[16] = {};
    for (int st = 0; st < 16; st++){
        int s0 = st*64;
        bool lower = (st < bx), upper = (st > bx);
        {
            const float* rp = upper ? rb : rf;
            const float* kp = upper ? kb : kf;
            #pragma unroll
            for (int i = 0; i < 16; i++){
                int e = tid + i*256; int rr = e >> 6, cc = e & 63;
                rs[rr][cc] = rp[hb + (size_t)(t0+rr)*64 + cc];
                ks[rr][cc] = kp[hb + (size_t)(s0+rr)*64 + cc];
            }
            __syncthreads();
            #pragma unroll
            for (int i = 0; i < 16; i++){
                int e = tid + i*256; int rr = e >> 6, cc = e & 63;
                float sum = 0.f;
                #pragma unroll
                for (int kk = 0; kk < 64; kk++) sum += rs[rr][kk]*ks[cc][kk];
                bool keep = upper || lower || (rr >= cc);
                at[rr][cc] = keep ? sum : 0.f;
            }
            __syncthreads();
        }
        if (st == bx){
            #pragma unroll
            for (int i = 0; i < 16; i++){
                int e = tid + i*256; int rr = e >> 6, cc = e & 63;
                rs[rr][cc] = rb[hb + (size_t)(t0+rr)*64 + cc];
                ks[rr][cc] = kb[hb + (size_t)(s0+rr)*64 + cc];
            }
            __syncthreads();
            #pragma unroll
            for (int i = 0; i < 16; i++){
                int e = tid + i*256; int rr = e >> 6, cc = e & 63;
                if (rr < cc){
                    float sum = 0.f;
                    #pragma unroll
                    for (int kk = 0; kk < 64; kk++) sum += rs[rr][kk]*ks[cc][kk];
                    at[rr][cc] = sum;
                }
            }
            __syncthreads();
        }
        #pragma unroll
        for (int i = 0; i < 16; i++){
            int e = tid + i*256; int rr = e >> 6, cc = e & 63;
            ks[rr][cc] = X[hb + (size_t)(s0+rr)*64 + cc];
        }
        __syncthreads();
        #pragma unroll 8
        for (int s = 0; s < 64; s++){
            float a = at[tq][s];
            #pragma unroll
            for (int j = 0; j < 16; j++) acc[j] += a * ks[s][kg*16+j];
        }
        __syncthreads();
    }
    #pragma unroll
    for (int j = 0; j < 16; j++)
        y[hb + (size_t)(t0+tq)*64 + kg*16+j] = acc[j];
}

// ---------------- GroupNorm + gate ----------------
__global__ void k_gn(const float* __restrict__ y, const float* __restrict__ g,
                     const float* __restrict__ lnw, const float* __restrict__ lnb,
                     float* __restrict__ z){
    int gw = (blockIdx.x*256 + threadIdx.x) >> 6;
    int lane = threadIdx.x & 63;
    if (gw >= CB*CT*CH) return;
    int h = gw % CH; int bt = gw / CH;
    int b = bt / CT, t = bt % CT;
    int bh = b*CH + h;
    float yv = y[((size_t)bh*CT + t)*64 + lane];
    float s1 = yv, s2 = yv*yv;
    #pragma unroll
    for (int off = 32; off; off >>= 1){ s1 += __shfl_xor(s1, off); s2 += __shfl_xor(s2, off); }
    float mu = s1 * (1.f/64.f);
    float var = s2 * (1.f/64.f) - mu*mu;
    float inv = rsqrtf(var + 6.4e-4f);
    int d = h*64 + lane;
    float yn = (yv - mu)*inv*lnw[d] + lnb[d];
    z[(size_t)bt*CD + d] = yn * g[(size_t)bt*CD + d];
}

extern "C" void kernel_launch(void* const* d_in, const int* in_sizes, int n_in,
                              void* d_out, int out_size, void* d_ws, size_t ws_size,
                              hipStream_t stream){
    const float* x          = (const float*)d_in[0];
    const float* tmx        = (const float*)d_in[1];
    const float* tmw        = (const float*)d_in[2];
    const float* tmk        = (const float*)d_in[3];
    const float* tmv        = (const float*)d_in[4];
    const float* tmr        = (const float*)d_in[5];
    const float* tmg        = (const float*)d_in[6];
    const float* maa_w1     = (const float*)d_in[7];
    const float* maa_w2     = (const float*)d_in[8];
    const float* time_decay = (const float*)d_in[9];
    const float* decay_w1   = (const float*)d_in[10];
    const float* decay_w2   = (const float*)d_in[11];
    const float* lucid_temp = (const float*)d_in[12];
    const float* Wr         = (const float*)d_in[13];
    const float* Wk         = (const float*)d_in[14];
    const float* Wv         = (const float*)d_in[15];
    const float* Wg         = (const float*)d_in[16];
    const float* Wo         = (const float*)d_in[17];
    const float* lnw        = (const float*)d_in[18];
    const float* lnb        = (const float*)d_in[19];
    float* out = (float*)d_out;
    float* ws  = (float*)d_ws;

    const size_t S = (size_t)CB*CT*CD;  // 3,145,728 floats (12.58 MB)
    // 10 full-size buffers with verified reuse chain:
    float* b0 = ws;          // dxprev -> wbuf
    float* b1 = ws + 1*S;    // xxx -> xw -> rf
    float* b2 = ws + 2*S;    // xk -> kf
    float* b3 = ws + 3*S;    // xv -> rb
    float* b4 = ws + 4*S;    // xr -> kn
    float* b5 = ws + 5*S;    // xg -> X (Pv)
    float* b6 = ws + 6*S;    // rbuf -> y
    float* b7 = ws + 7*S;    // kbuf -> z
    float* b8 = ws + 8*S;    // vbuf -> kb
    float* b9 = ws + 9*S;    // gbuf
    float* mbuf = ws + 10*S; // m (4096x160), then decay tanh (4096x64)
    const size_t MB_F = 4096*160;
    size_t base_f = 10*S + MB_F;

    // chunked P/invL sized to available workspace
    const size_t per_bh = (size_t)CT*CT + 16*NB*NB;  // P block + invL block
    size_t avail = ws_size / sizeof(float);
    int G = 1;
    if (avail > base_f + per_bh){
        size_t g = (avail - base_f) / per_bh;
        G = (g >= CBH) ? CBH : (int)g;
        if (G < 1) G = 1;
    }
    float* P    = ws + base_f;
    float* invL = P + (size_t)G*CT*CT;

    float* dxprev = b0; float* xxx = b1;
    float* xw = b1; float* xk = b2; float* xv = b3; float* xr = b4; float* xg = b5;
    float* rbuf = b6; float* kbuf = b7; float* vbuf = b8; float* gbuf = b9; float* wbuf = b0;
    float* kn = b4; float* X = b5;
    float* rf = b1; float* kf = b2; float* rb = b3; float* kb = b8;
    float* ybuf = b6; float* zbuf = b7;

    k_shift<<<dim3((CB*CT*CD + 255)/256), 256, 0, stream>>>(x, tmx, dxprev, xxx);
    k_gemm<1><<<dim3(3, 32), 256, 0, stream>>>(xxx, maa_w1, nullptr, mbuf, 4096, 160, 768);
    k_mix5<<<dim3(3, 4096), 256, 0, stream>>>(x, dxprev, mbuf, tmw, tmk, tmv, tmr, tmg,
                                              maa_w2, xw, xk, xv, xr, xg);
    k_gemm<0><<<dim3(12, 32), 256, 0, stream>>>(xr, Wr, nullptr, rbuf, 4096, 768, 768);
    k_gemm<0><<<dim3(12, 32), 256, 0, stream>>>(xk, Wk, nullptr, kbuf, 4096, 768, 768);
    k_gemm<0><<<dim3(12, 32), 256, 0, stream>>>(xv, Wv, nullptr, vbuf, 4096, 768, 768);
    k_gemm<2><<<dim3(12, 32), 256, 0, stream>>>(xg, Wg, nullptr, gbuf, 4096, 768, 768);
    k_gemm<1><<<dim3(1, 32), 256, 0, stream>>>(xw, decay_w1, nullptr, mbuf, 4096, 64, 768);
    k_gemm<3><<<dim3(12, 32), 256, 0, stream>>>(mbuf, decay_w2, time_decay, wbuf, 4096, 768, 64);

    k_knvx<<<dim3((CB*CH*CT*64)/256), 256, 0, stream>>>(kbuf, vbuf, kn, X);
    k_scan<<<dim3(CBH), 1024, 0, stream>>>(rbuf, kbuf, wbuf, rf, kf, rb, kb);

    for (int bh0 = 0; bh0 < CBH; bh0 += G){
        int Gc = (CBH - bh0 < G) ? (CBH - bh0) : G;
        k_gram<<<dim3(16, 16, Gc), 256, 0, stream>>>(kn, lucid_temp, P, bh0);
        for (int jb = 0; jb < 16; jb++){
            k_potrf<<<dim3(Gc), 256, 0, stream>>>(P, invL, jb);
            int rows = CT - (jb+1)*NB;
            if (rows > 0){
                k_trsm<<<dim3(rows/64, Gc), 256, 0, stream>>>(P, invL, jb);
                k_syrk<<<dim3(rows/64, rows/64, Gc), 256, 0, stream>>>(P, jb);
            }
        }
        k_fwd<<<dim3(Gc), 256, 0, stream>>>(P, invL, X, bh0);
        k_bwd<<<dim3(Gc), 256, 0, stream>>>(P, invL, X, bh0);
    }

    k_apv<<<dim3(16, CBH), 256, 0, stream>>>(rf, kf, rb, kb, X, ybuf);
    k_gn<<<dim3((CB*CT*CH*64)/256), 256, 0, stream>>>(ybuf, gbuf, lnw, lnb, zbuf);
    k_gemm<0><<<dim3(12, 32), 256, 0, stream>>>(zbuf, Wo, nullptr, out, 4096, 768, 768);
}

// Round 3
// 9377.706 us; speedup vs baseline: 3.3207x; 3.3207x over previous
//
#include <hip/hip_runtime.h>
#include <math.h>

#define CB 4
#define CT 1024
#define CD 768
#define CH 12
#define CK 64
#define CBH (CB*CH)
#define NB 64

// ---------------- elementwise: token shift + xxx ----------------
__global__ void k_shift(const float* __restrict__ x, const float* __restrict__ tmx,
                        float* __restrict__ dxprev, float* __restrict__ xxx){
    int idx = blockIdx.x*256 + threadIdx.x;
    if (idx >= CB*CT*CD) return;
    int d = idx % CD;
    int bt = idx / CD;
    int t = bt % CT;
    float xc = x[idx];
    float xl = (t > 0)      ? x[idx - CD] : 0.f;
    float xr = (t < CT-1)   ? x[idx + CD] : 0.f;
    float dx = 0.5f*(xl + xr) - xc;
    dxprev[idx] = dx;
    xxx[idx] = xc + dx * tmx[d];
}

// ---------------- generic tiled fp32 GEMM ----------------
// C[M,N] = epilogue(A[M,K] @ B[K,N]); MODE 0 plain, 1 tanh, 2 silu, 3 +bias[n]
template<int MODE>
__global__ void k_gemm(const float* __restrict__ A, const float* __restrict__ Bm,
                       const float* __restrict__ bias, float* __restrict__ C,
                       int M, int N, int Kd){
    __shared__ float As[16][128];
    __shared__ float Bs[16][64];
    int tid = threadIdx.x;
    int m0 = blockIdx.y * 128, n0 = blockIdx.x * 64;
    int tn = (tid & 15) * 4;
    int tm = (tid >> 4) * 8;
    float acc[8][4] = {};
    for (int k0 = 0; k0 < Kd; k0 += 16){
        #pragma unroll
        for (int i = 0; i < 8; i++){
            int e = tid + i*256;
            int r = e >> 4, c = e & 15;
            As[c][r] = A[(size_t)(m0+r)*Kd + k0 + c];
        }
        #pragma unroll
        for (int i = 0; i < 4; i++){
            int e = tid + i*256;
            int r = e >> 6, c = e & 63;
            float bv = 0.f;
            if (n0 + c < N) bv = Bm[(size_t)(k0+r)*N + n0 + c];
            Bs[r][c] = bv;
        }
        __syncthreads();
        #pragma unroll
        for (int kk = 0; kk < 16; kk++){
            float a0[8], b0[4];
            #pragma unroll
            for (int i = 0; i < 8; i++) a0[i] = As[kk][tm+i];
            #pragma unroll
            for (int j = 0; j < 4; j++) b0[j] = Bs[kk][tn+j];
            #pragma unroll
            for (int i = 0; i < 8; i++)
                #pragma unroll
                for (int j = 0; j < 4; j++) acc[i][j] += a0[i]*b0[j];
        }
        __syncthreads();
    }
    #pragma unroll
    for (int i = 0; i < 8; i++)
        #pragma unroll
        for (int j = 0; j < 4; j++){
            int mm = m0 + tm + i, nn = n0 + tn + j;
            if (nn < N){
                float v = acc[i][j];
                if (MODE == 1) v = tanhf(v);
                else if (MODE == 2) v = v / (1.f + expf(-v));
                else if (MODE == 3) v += bias[nn];
                C[(size_t)mm*N + nn] = v;
            }
        }
}

// ---------------- 5-way low-rank mix ----------------
__global__ void k_mix5(const float* __restrict__ x, const float* __restrict__ dxprev,
                       const float* __restrict__ m,
                       const float* __restrict__ tmw, const float* __restrict__ tmk,
                       const float* __restrict__ tmv, const float* __restrict__ tmr,
                       const float* __restrict__ tmg, const float* __restrict__ w2,
                       float* __restrict__ xw, float* __restrict__ xk, float* __restrict__ xv,
                       float* __restrict__ xr, float* __restrict__ xg){
    __shared__ float ms[160];
    int i = blockIdx.y;
    int j = blockIdx.x*256 + threadIdx.x;
    if (threadIdx.x < 160) ms[threadIdx.x] = m[(size_t)i*160 + threadIdx.x];
    __syncthreads();
    float xc = x[(size_t)i*CD + j], dx = dxprev[(size_t)i*CD + j];
    const float* tms[5] = {tmw, tmk, tmv, tmr, tmg};
    float* outs[5] = {xw, xk, xv, xr, xg};
    #pragma unroll
    for (int c = 0; c < 5; c++){
        float s = tms[c][j];
        const float* w2c = w2 + (size_t)c*32*CD + j;
        #pragma unroll
        for (int dm = 0; dm < 32; dm++) s += ms[c*32+dm] * w2c[(size_t)dm*CD];
        outs[c][(size_t)i*CD + j] = xc + dx*s;
    }
}

// ---------------- normalize k, stage v into X (head layout) ----------------
__global__ void k_knvx(const float* __restrict__ k, const float* __restrict__ v,
                       float* __restrict__ kn, float* __restrict__ X){
    int gw = (blockIdx.x*256 + threadIdx.x) >> 6;
    int lane = threadIdx.x & 63;
    if (gw >= CB*CH*CT) return;
    int t = gw % CT; int bh = gw / CT; int h = bh % CH; int b = bh / CH;
    size_t src = ((size_t)(b*CT + t))*CD + h*64 + lane;
    float kv = k[src];
    float ss = kv*kv;
    #pragma unroll
    for (int off = 32; off; off >>= 1) ss += __shfl_xor(ss, off);
    float nrm = fmaxf(sqrtf(ss), 1e-12f);
    size_t dst = ((size_t)bh*CT + t)*64 + lane;
    kn[dst] = kv / nrm;
    X[dst]  = v[src];
}

// ---------------- per-(b,h) decay scan -> rf,kf,rb,kb ----------------
__global__ void __launch_bounds__(1024) k_scan(const float* __restrict__ r, const float* __restrict__ k,
                       const float* __restrict__ w,
                       float* __restrict__ rf, float* __restrict__ kf,
                       float* __restrict__ rb, float* __restrict__ kb){
    __shared__ float s[1024];
    __shared__ float refs[2];
    int bh = blockIdx.x; int h = bh % CH; int b = bh / CH;
    int t = threadIdx.x;
    size_t base_btd = ((size_t)(b*CT + t))*CD + h*64;
    size_t base_hk  = ((size_t)bh*CT + t)*64;
    for (int kk = 0; kk < 64; kk++){
        float wv = -expf(w[base_btd + kk]);
        s[t] = wv;
        __syncthreads();
        for (int off = 1; off < 1024; off <<= 1){
            float add = (t >= off) ? s[t-off] : 0.f;
            __syncthreads();
            s[t] += add;
            __syncthreads();
        }
        float cs = s[t];
        if (t == 512){ refs[0] = cs; refs[1] = wv; }
        __syncthreads();
        float ref_f = refs[0];
        float ref_b = refs[0] - refs[1];
        float csf = fminf(fmaxf(cs - ref_f, -60.f), 60.f);
        float csb = fminf(fmaxf((cs - wv) - ref_b, -60.f), 60.f);
        float rv = r[base_btd + kk], kv = k[base_btd + kk];
        rf[base_hk + kk] = rv * expf(csf);
        kf[base_hk + kk] = kv * expf(-csf);
        rb[base_hk + kk] = rv * expf(-csb);
        kb[base_hk + kk] = kv * expf(csb);
        __syncthreads();
    }
}

// ---------------- P(lower) = I + exp(clip(temp * kn knT)) (chunk-local P) ----------------
__global__ void k_gram(const float* __restrict__ kn, const float* __restrict__ lucid_temp,
                       float* __restrict__ P, int bh0){
    int t0 = blockIdx.y*64, s0 = blockIdx.x*64;
    if (t0 < s0) return;  // lower triangle only — upper is never read
    __shared__ float tA[64][65];
    __shared__ float tB[64][65];
    int lbh = blockIdx.z; int gbh = bh0 + lbh; int h = gbh % CH;
    int tid = threadIdx.x;
    #pragma unroll
    for (int i = 0; i < 16; i++){
        int e = tid + i*256; int rr = e >> 6, cc = e & 63;
        tA[rr][cc] = kn[((size_t)gbh*CT + t0+rr)*64 + cc];
        tB[rr][cc] = kn[((size_t)gbh*CT + s0+rr)*64 + cc];
    }
    __syncthreads();
    float tv = lucid_temp[h];
    tv = (tv > 20.f) ? tv : log1pf(expf(tv));
    int ty = (tid >> 4)*4, tx = (tid & 15)*4;
    float acc[4][4] = {};
    #pragma unroll
    for (int kk = 0; kk < 64; kk++){
        float a0[4], b0[4];
        #pragma unroll
        for (int i = 0; i < 4; i++){ a0[i] = tA[ty+i][kk]; b0[i] = tB[tx+i][kk]; }
        #pragma unroll
        for (int i = 0; i < 4; i++)
            #pragma unroll
            for (int j = 0; j < 4; j++) acc[i][j] += a0[i]*b0[j];
    }
    size_t pbase = (size_t)lbh*CT*CT;
    #pragma unroll
    for (int i = 0; i < 4; i++)
        #pragma unroll
        for (int j = 0; j < 4; j++){
            int tt = t0+ty+i, ss = s0+tx+j;
            float gv = fminf(fmaxf(tv*acc[i][j], -20.f), 20.f);
            P[pbase + (size_t)tt*CT + ss] = expf(gv) + ((tt == ss) ? 1.f : 0.f);
        }
}

// ---------------- Cholesky: factor diagonal block + invert (chunk-local) ----------------
__global__ void k_potrf(float* __restrict__ P, float* __restrict__ invL, int jb){
    __shared__ float s[NB][NB+1];
    __shared__ float inv[NB][NB+1];
    int bh = blockIdx.x; int tid = threadIdx.x;
    size_t base = (size_t)bh*CT*CT;
    int j0 = jb*NB;
    #pragma unroll
    for (int i = 0; i < 16; i++){
        int e = tid + i*256; int rr = e >> 6, cc = e & 63;
        int r = (rr >= cc) ? rr : cc, c = (rr >= cc) ? cc : rr;
        s[rr][cc] = P[base + (size_t)(j0+r)*CT + (j0+c)];
    }
    __syncthreads();
    for (int j = 0; j < NB; j++){
        if (tid == 0) s[j][j] = sqrtf(fmaxf(s[j][j], 1e-30f));
        __syncthreads();
        float dj = s[j][j];
        for (int i = j+1+tid; i < NB; i += 256) s[i][j] /= dj;
        __syncthreads();
        int n = NB-1-j;
        for (int e = tid; e < n*n; e += 256){
            int ii = j+1 + e / n, cc2 = j+1 + e % n;
            s[ii][cc2] -= s[ii][j]*s[cc2][j];
        }
        __syncthreads();
    }
    if (tid < NB){
        int c = tid;
        for (int j = 0; j < c; j++) inv[j][c] = 0.f;
        for (int j = c; j < NB; j++){
            float sum = (j == c) ? 1.f : 0.f;
            for (int kk = c; kk < j; kk++) sum -= s[j][kk]*inv[kk][c];
            inv[j][c] = sum / s[j][j];
        }
    }
    __syncthreads();
    float* invp = invL + ((size_t)bh*16 + jb)*NB*NB;
    #pragma unroll
    for (int i = 0; i < 16; i++){
        int e = tid + i*256; int rr = e >> 6, cc = e & 63;
        if (cc <= rr) P[base + (size_t)(j0+rr)*CT + (j0+cc)] = s[rr][cc];
        invp[rr*NB + cc] = inv[rr][cc];
    }
}

// ---------------- TRSM: panel = A21 @ invL11^T (chunk-local) ----------------
__global__ void k_trsm(float* __restrict__ P, const float* __restrict__ invL, int jb){
    __shared__ float a[64][65];
    __shared__ float iv[64][65];
    int bh = blockIdx.y;
    int r0 = (jb+1)*NB + blockIdx.x*64;
    int j0 = jb*NB;
    size_t base = (size_t)bh*CT*CT;
    int tid = threadIdx.x;
    const float* invp = invL + ((size_t)bh*16 + jb)*NB*NB;
    #pragma unroll
    for (int i = 0; i < 16; i++){
        int e = tid + i*256; int rr = e >> 6, cc = e & 63;
        a[rr][cc]  = P[base + (size_t)(r0+rr)*CT + j0 + cc];
        iv[rr][cc] = invp[rr*NB + cc];
    }
    __syncthreads();
    int ty = (tid >> 4)*4, tx = (tid & 15)*4;
    float acc[4][4] = {};
    #pragma unroll
    for (int kk = 0; kk < 64; kk++){
        float a0[4], b0[4];
        #pragma unroll
        for (int i = 0; i < 4; i++){ a0[i] = a[ty+i][kk]; b0[i] = iv[tx+i][kk]; }
        #pragma unroll
        for (int i = 0; i < 4; i++)
            #pragma unroll
            for (int j = 0; j < 4; j++) acc[i][j] += a0[i]*b0[j];
    }
    __syncthreads();
    #pragma unroll
    for (int i = 0; i < 4; i++)
        #pragma unroll
        for (int j = 0; j < 4; j++)
            P[base + (size_t)(r0+ty+i)*CT + j0+tx+j] = acc[i][j];
}

// ---------------- SYRK: A22 -= L21 @ L21^T (lower tiles, chunk-local) ----------------
__global__ void k_syrk(float* __restrict__ P, int jb){
    int ti = blockIdx.y, tj = blockIdx.x;
    if (tj > ti) return;
    int bh = blockIdx.z;
    int off = (jb+1)*NB;
    int r0 = off + ti*64, c0 = off + tj*64;
    int j0 = jb*NB;
    size_t base = (size_t)bh*CT*CT;
    __shared__ float La[64][65], Lb[64][65];
    int tid = threadIdx.x;
    #pragma unroll
    for (int i = 0; i < 16; i++){
        int e = tid + i*256; int rr = e >> 6, cc = e & 63;
        La[rr][cc] = P[base + (size_t)(r0+rr)*CT + j0 + cc];
        Lb[rr][cc] = P[base + (size_t)(c0+rr)*CT + j0 + cc];
    }
    __syncthreads();
    int ty = (tid >> 4)*4, tx = (tid & 15)*4;
    float acc[4][4] = {};
    #pragma unroll
    for (int kk = 0; kk < 64; kk++){
        float a0[4], b0[4];
        #pragma unroll
        for (int i = 0; i < 4; i++){ a0[i] = La[ty+i][kk]; b0[i] = Lb[tx+i][kk]; }
        #pragma unroll
        for (int i = 0; i < 4; i++)
            #pragma unroll
            for (int j = 0; j < 4; j++) acc[i][j] += a0[i]*b0[j];
    }
    #pragma unroll
    for (int i = 0; i < 4; i++)
        #pragma unroll
        for (int j = 0; j < 4; j++)
            P[base + (size_t)(r0+ty+i)*CT + c0+tx+j] -= acc[i][j];
}

// ---------------- block substitution: diag apply X[jb] = invL(^T) @ X[jb] ----------------
template<int TRANS>
__global__ void k_sub_diag(const float* __restrict__ invL, float* __restrict__ X,
                           int bh0, int jb){
    __shared__ float Ls[64][65], xs[64][65];
    int bh = blockIdx.x, tid = threadIdx.x;
    const float* invp = invL + ((size_t)bh*16 + jb)*4096;
    float* Xb = X + ((size_t)(bh0 + bh)*CT + jb*64)*64;
    #pragma unroll
    for (int i = 0; i < 16; i++){
        int e = tid + i*256, rr = e >> 6, cc = e & 63;
        Ls[rr][cc] = invp[rr*64 + cc];
        xs[rr][cc] = Xb[(size_t)rr*64 + cc];
    }
    __syncthreads();
    int ty = (tid >> 4)*4, tx = (tid & 15)*4;
    float acc[4][4] = {};
    #pragma unroll
    for (int kk = 0; kk < 64; kk++){
        float a0[4], b0[4];
        #pragma unroll
        for (int i = 0; i < 4; i++){
            a0[i] = TRANS ? Ls[kk][ty+i] : Ls[ty+i][kk];
            b0[i] = xs[kk][tx+i];
        }
        #pragma unroll
        for (int i = 0; i < 4; i++)
            #pragma unroll
            for (int j = 0; j < 4; j++) acc[i][j] += a0[i]*b0[j];
    }
    #pragma unroll
    for (int i = 0; i < 4; i++)
        #pragma unroll
        for (int j = 0; j < 4; j++)
            Xb[(size_t)(ty+i)*64 + tx+j] = acc[i][j];
}

// ---------------- block substitution: trailing update ----------------
// TRANS=0 (fwd): X[ib] -= L[ib][jb] @ X[jb],    ib = jb+1+blockIdx.x
// TRANS=1 (bwd): X[ib] -= L[jb][ib]^T @ X[jb],  ib = blockIdx.x
template<int TRANS>
__global__ void k_sub_upd(const float* __restrict__ P, float* __restrict__ X,
                          int bh0, int jb){
    __shared__ float Ls[64][65], ys[64][65];
    int bh = blockIdx.y, tid = threadIdx.x;
    int ib = TRANS ? blockIdx.x : (jb+1+blockIdx.x);
    size_t base = (size_t)bh*CT*CT;
    const float* Lblk = P + base + (TRANS ? ((size_t)(jb*64)*CT + ib*64)
                                          : ((size_t)(ib*64)*CT + jb*64));
    const float* Xs = X + ((size_t)(bh0 + bh)*CT + jb*64)*64;
    float*       Xd = X + ((size_t)(bh0 + bh)*CT + ib*64)*64;
    #pragma unroll
    for (int i = 0; i < 16; i++){
        int e = tid + i*256, rr = e >> 6, cc = e & 63;
        Ls[rr][cc] = Lblk[(size_t)rr*CT + cc];
        ys[rr][cc] = Xs[(size_t)rr*64 + cc];
    }
    __syncthreads();
    int ty = (tid >> 4)*4, tx = (tid & 15)*4;
    float acc[4][4] = {};
    #pragma unroll
    for (int kk = 0; kk < 64; kk++){
        float a0[4], b0[4];
        #pragma unroll
        for (int i = 0; i < 4; i++){
            a0[i] = TRANS ? Ls[kk][ty+i] : Ls[ty+i][kk];
            b0[i] = ys[kk][tx+i];
        }
        #pragma unroll
        for (int i = 0; i < 4; i++)
            #pragma unroll
            for (int j = 0; j < 4; j++) acc[i][j] += a0[i]*b0[j];
    }
    #pragma unroll
    for (int i = 0; i < 4; i++)
        #pragma unroll
        for (int j = 0; j < 4; j++)
            Xd[(size_t)(ty+i)*64 + tx+j] -= acc[i][j];
}

// ---------------- y = (tril(rf kf^T) + triu(rb kb^T,1)) @ Pv ----------------
__global__ void k_apv(const float* __restrict__ rf, const float* __restrict__ kf,
                      const float* __restrict__ rb, const float* __restrict__ kb,
                      const float* __restrict__ X, float* __restrict__ y){
    __shared__ float rs[64][65];
    __shared__ float ks[64][65];
    __shared__ float at[64][65];
    int bh = blockIdx.y;
    int bx = blockIdx.x;
    int t0 = bx * 64;
    int tid = threadIdx.x;
    size_t hb = (size_t)bh*CT*64;
    int tq = tid & 63, kg = tid >> 6;
    float acc[16] = {};
    for (int st = 0; st < 16; st++){
        int s0 = st*64;
        bool lower = (st < bx), upper = (st > bx);
        {
            const float* rp = upper ? rb : rf;
            const float* kp = upper ? kb : kf;
            #pragma unroll
            for (int i = 0; i < 16; i++){
                int e = tid + i*256; int rr = e >> 6, cc = e & 63;
                rs[rr][cc] = rp[hb + (size_t)(t0+rr)*64 + cc];
                ks[rr][cc] = kp[hb + (size_t)(s0+rr)*64 + cc];
            }
            __syncthreads();
            #pragma unroll
            for (int i = 0; i < 16; i++){
                int e = tid + i*256; int rr = e >> 6, cc = e & 63;
                float sum = 0.f;
                #pragma unroll
                for (int kk = 0; kk < 64; kk++) sum += rs[rr][kk]*ks[cc][kk];
                bool keep = upper || lower || (rr >= cc);
                at[rr][cc] = keep ? sum : 0.f;
            }
            __syncthreads();
        }
        if (st == bx){
            #pragma unroll
            for (int i = 0; i < 16; i++){
                int e = tid + i*256; int rr = e >> 6, cc = e & 63;
                rs[rr][cc] = rb[hb + (size_t)(t0+rr)*64 + cc];
                ks[rr][cc] = kb[hb + (size_t)(s0+rr)*64 + cc];
            }
            __syncthreads();
            #pragma unroll
            for (int i = 0; i < 16; i++){
                int e = tid + i*256; int rr = e >> 6, cc = e & 63;
                if (rr < cc){
                    float sum = 0.f;
                    #pragma unroll
                    for (int kk = 0; kk < 64; kk++) sum += rs[rr][kk]*ks[cc][kk];
                    at[rr][cc] = sum;
                }
            }
            __syncthreads();
        }
        #pragma unroll
        for (int i = 0; i < 16; i++){
            int e = tid + i*256; int rr = e >> 6, cc = e & 63;
            ks[rr][cc] = X[hb + (size_t)(s0+rr)*64 + cc];
        }
        __syncthreads();
        #pragma unroll 8
        for (int s = 0; s < 64; s++){
            float a = at[tq][s];
            #pragma unroll
            for (int j = 0; j < 16; j++) acc[j] += a * ks[s][kg*16+j];
        }
        __syncthreads();
    }
    #pragma unroll
    for (int j = 0; j < 16; j++)
        y[hb + (size_t)(t0+tq)*64 + kg*16+j] = acc[j];
}

// ---------------- GroupNorm + gate ----------------
__global__ void k_gn(const float* __restrict__ y, const float* __restrict__ g,
                     const float* __restrict__ lnw, const float* __restrict__ lnb,
                     float* __restrict__ z){
    int gw = (blockIdx.x*256 + threadIdx.x) >> 6;
    int lane = threadIdx.x & 63;
    if (gw >= CB*CT*CH) return;
    int h = gw % CH; int bt = gw / CH;
    int b = bt / CT, t = bt % CT;
    int bh = b*CH + h;
    float yv = y[((size_t)bh*CT + t)*64 + lane];
    float s1 = yv, s2 = yv*yv;
    #pragma unroll
    for (int off = 32; off; off >>= 1){ s1 += __shfl_xor(s1, off); s2 += __shfl_xor(s2, off); }
    float mu = s1 * (1.f/64.f);
    float var = s2 * (1.f/64.f) - mu*mu;
    float inv = rsqrtf(var + 6.4e-4f);
    int d = h*64 + lane;
    float yn = (yv - mu)*inv*lnw[d] + lnb[d];
    z[(size_t)bt*CD + d] = yn * g[(size_t)bt*CD + d];
}

extern "C" void kernel_launch(void* const* d_in, const int* in_sizes, int n_in,
                              void* d_out, int out_size, void* d_ws, size_t ws_size,
                              hipStream_t stream){
    const float* x          = (const float*)d_in[0];
    const float* tmx        = (const float*)d_in[1];
    const float* tmw        = (const float*)d_in[2];
    const float* tmk        = (const float*)d_in[3];
    const float* tmv        = (const float*)d_in[4];
    const float* tmr        = (const float*)d_in[5];
    const float* tmg        = (const float*)d_in[6];
    const float* maa_w1     = (const float*)d_in[7];
    const float* maa_w2     = (const float*)d_in[8];
    const float* time_decay = (const float*)d_in[9];
    const float* decay_w1   = (const float*)d_in[10];
    const float* decay_w2   = (const float*)d_in[11];
    const float* lucid_temp = (const float*)d_in[12];
    const float* Wr         = (const float*)d_in[13];
    const float* Wk         = (const float*)d_in[14];
    const float* Wv         = (const float*)d_in[15];
    const float* Wg         = (const float*)d_in[16];
    const float* Wo         = (const float*)d_in[17];
    const float* lnw        = (const float*)d_in[18];
    const float* lnb        = (const float*)d_in[19];
    float* out = (float*)d_out;
    float* ws  = (float*)d_ws;

    const size_t S = (size_t)CB*CT*CD;  // 3,145,728 floats (12.58 MB)
    float* b0 = ws;          // dxprev -> wbuf
    float* b1 = ws + 1*S;    // xxx -> xw -> rf
    float* b2 = ws + 2*S;    // xk -> kf
    float* b3 = ws + 3*S;    // xv -> rb
    float* b4 = ws + 4*S;    // xr -> kn
    float* b5 = ws + 5*S;    // xg -> X (Pv)
    float* b6 = ws + 6*S;    // rbuf -> y
    float* b7 = ws + 7*S;    // kbuf -> z
    float* b8 = ws + 8*S;    // vbuf -> kb
    float* b9 = ws + 9*S;    // gbuf
    float* mbuf = ws + 10*S; // m (4096x160), then decay tanh (4096x64)
    const size_t MB_F = 4096*160;
    size_t base_f = 10*S + MB_F;

    const size_t per_bh = (size_t)CT*CT + 16*NB*NB;
    size_t avail = ws_size / sizeof(float);
    int G = 1;
    if (avail > base_f + per_bh){
        size_t g = (avail - base_f) / per_bh;
        G = (g >= CBH) ? CBH : (int)g;
        if (G < 1) G = 1;
    }
    float* P    = ws + base_f;
    float* invL = P + (size_t)G*CT*CT;

    float* dxprev = b0; float* xxx = b1;
    float* xw = b1; float* xk = b2; float* xv = b3; float* xr = b4; float* xg = b5;
    float* rbuf = b6; float* kbuf = b7; float* vbuf = b8; float* gbuf = b9; float* wbuf = b0;
    float* kn = b4; float* X = b5;
    float* rf = b1; float* kf = b2; float* rb = b3; float* kb = b8;
    float* ybuf = b6; float* zbuf = b7;

    k_shift<<<dim3((CB*CT*CD + 255)/256), 256, 0, stream>>>(x, tmx, dxprev, xxx);
    k_gemm<1><<<dim3(3, 32), 256, 0, stream>>>(xxx, maa_w1, nullptr, mbuf, 4096, 160, 768);
    k_mix5<<<dim3(3, 4096), 256, 0, stream>>>(x, dxprev, mbuf, tmw, tmk, tmv, tmr, tmg,
                                              maa_w2, xw, xk, xv, xr, xg);
    k_gemm<0><<<dim3(12, 32), 256, 0, stream>>>(xr, Wr, nullptr, rbuf, 4096, 768, 768);
    k_gemm<0><<<dim3(12, 32), 256, 0, stream>>>(xk, Wk, nullptr, kbuf, 4096, 768, 768);
    k_gemm<0><<<dim3(12, 32), 256, 0, stream>>>(xv, Wv, nullptr, vbuf, 4096, 768, 768);
    k_gemm<2><<<dim3(12, 32), 256, 0, stream>>>(xg, Wg, nullptr, gbuf, 4096, 768, 768);
    k_gemm<1><<<dim3(1, 32), 256, 0, stream>>>(xw, decay_w1, nullptr, mbuf, 4096, 64, 768);
    k_gemm<3><<<dim3(12, 32), 256, 0, stream>>>(mbuf, decay_w2, time_decay, wbuf, 4096, 768, 64);

    k_knvx<<<dim3((CB*CH*CT*64)/256), 256, 0, stream>>>(kbuf, vbuf, kn, X);
    k_scan<<<dim3(CBH), 1024, 0, stream>>>(rbuf, kbuf, wbuf, rf, kf, rb, kb);

    for (int bh0 = 0; bh0 < CBH; bh0 += G){
        int Gc = (CBH - bh0 < G) ? (CBH - bh0) : G;
        k_gram<<<dim3(16, 16, Gc), 256, 0, stream>>>(kn, lucid_temp, P, bh0);
        for (int jb = 0; jb < 16; jb++){
            k_potrf<<<dim3(Gc), 256, 0, stream>>>(P, invL, jb);
            int rows = CT - (jb+1)*NB;
            if (rows > 0){
                k_trsm<<<dim3(rows/64, Gc), 256, 0, stream>>>(P, invL, jb);
                k_syrk<<<dim3(rows/64, rows/64, Gc), 256, 0, stream>>>(P, jb);
            }
        }
        // forward substitution: L Y = V
        for (int jb = 0; jb < 16; jb++){
            k_sub_diag<0><<<dim3(Gc), 256, 0, stream>>>(invL, X, bh0, jb);
            if (jb < 15)
                k_sub_upd<0><<<dim3(15-jb, Gc), 256, 0, stream>>>(P, X, bh0, jb);
        }
        // backward substitution: L^T Z = Y
        for (int jb = 15; jb >= 0; jb--){
            k_sub_diag<1><<<dim3(Gc), 256, 0, stream>>>(invL, X, bh0, jb);
            if (jb > 0)
                k_sub_upd<1><<<dim3(jb, Gc), 256, 0, stream>>>(P, X, bh0, jb);
        }
    }

    k_apv<<<dim3(16, CBH), 256, 0, stream>>>(rf, kf, rb, kb, X, ybuf);
    k_gn<<<dim3((CB*CT*CH*64)/256), 256, 0, stream>>>(ybuf, gbuf, lnw, lnb, zbuf);
    k_gemm<0><<<dim3(12, 32), 256, 0, stream>>>(zbuf, Wo, nullptr, out, 4096, 768, 768);
}

// Round 4
// 8629.149 us; speedup vs baseline: 3.6088x; 1.0867x over previous
//
#include <hip/hip_runtime.h>
#include <math.h>

#define CB 4
#define CT 1024
#define CD 768
#define CH 12
#define CK 64
#define CBH (CB*CH)
#define NB 64

// cooperative 64x64 tile load: global (row-major, given stride) -> LDS [64][65]
#define LOAD_TILE(dst, src, stride) { \
    _Pragma("unroll") \
    for (int i_ = 0; i_ < 4; i_++){ \
        int rr_ = (tid>>4) + i_*16, cc_ = (tid&15)*4; \
        float4 v_ = *(const float4*)((src) + (size_t)rr_*(stride) + cc_); \
        dst[rr_][cc_+0]=v_.x; dst[rr_][cc_+1]=v_.y; dst[rr_][cc_+2]=v_.z; dst[rr_][cc_+3]=v_.w; \
    } }

// ---------------- elementwise: token shift + xxx ----------------
__global__ void k_shift(const float* __restrict__ x, const float* __restrict__ tmx,
                        float* __restrict__ dxprev, float* __restrict__ xxx){
    int idx = blockIdx.x*256 + threadIdx.x;
    if (idx >= CB*CT*CD) return;
    int d = idx % CD;
    int bt = idx / CD;
    int t = bt % CT;
    float xc = x[idx];
    float xl = (t > 0)      ? x[idx - CD] : 0.f;
    float xr = (t < CT-1)   ? x[idx + CD] : 0.f;
    float dx = 0.5f*(xl + xr) - xc;
    dxprev[idx] = dx;
    xxx[idx] = xc + dx * tmx[d];
}

// ---------------- generic tiled fp32 GEMM ----------------
template<int MODE>
__global__ void k_gemm(const float* __restrict__ A, const float* __restrict__ Bm,
                       const float* __restrict__ bias, float* __restrict__ C,
                       int M, int N, int Kd){
    __shared__ float As[16][128];
    __shared__ float Bs[16][64];
    int tid = threadIdx.x;
    int m0 = blockIdx.y * 128, n0 = blockIdx.x * 64;
    int tn = (tid & 15) * 4;
    int tm = (tid >> 4) * 8;
    float acc[8][4] = {};
    for (int k0 = 0; k0 < Kd; k0 += 16){
        #pragma unroll
        for (int i = 0; i < 8; i++){
            int e = tid + i*256;
            int r = e >> 4, c = e & 15;
            As[c][r] = A[(size_t)(m0+r)*Kd + k0 + c];
        }
        #pragma unroll
        for (int i = 0; i < 4; i++){
            int e = tid + i*256;
            int r = e >> 6, c = e & 63;
            float bv = 0.f;
            if (n0 + c < N) bv = Bm[(size_t)(k0+r)*N + n0 + c];
            Bs[r][c] = bv;
        }
        __syncthreads();
        #pragma unroll
        for (int kk = 0; kk < 16; kk++){
            float a0[8], b0[4];
            #pragma unroll
            for (int i = 0; i < 8; i++) a0[i] = As[kk][tm+i];
            #pragma unroll
            for (int j = 0; j < 4; j++) b0[j] = Bs[kk][tn+j];
            #pragma unroll
            for (int i = 0; i < 8; i++)
                #pragma unroll
                for (int j = 0; j < 4; j++) acc[i][j] += a0[i]*b0[j];
        }
        __syncthreads();
    }
    #pragma unroll
    for (int i = 0; i < 8; i++)
        #pragma unroll
        for (int j = 0; j < 4; j++){
            int mm = m0 + tm + i, nn = n0 + tn + j;
            if (nn < N){
                float v = acc[i][j];
                if (MODE == 1) v = tanhf(v);
                else if (MODE == 2) v = v / (1.f + expf(-v));
                else if (MODE == 3) v += bias[nn];
                C[(size_t)mm*N + nn] = v;
            }
        }
}

// ---------------- 5-way low-rank mix ----------------
__global__ void k_mix5(const float* __restrict__ x, const float* __restrict__ dxprev,
                       const float* __restrict__ m,
                       const float* __restrict__ tmw, const float* __restrict__ tmk,
                       const float* __restrict__ tmv, const float* __restrict__ tmr,
                       const float* __restrict__ tmg, const float* __restrict__ w2,
                       float* __restrict__ xw, float* __restrict__ xk, float* __restrict__ xv,
                       float* __restrict__ xr, float* __restrict__ xg){
    __shared__ float ms[160];
    int i = blockIdx.y;
    int j = blockIdx.x*256 + threadIdx.x;
    if (threadIdx.x < 160) ms[threadIdx.x] = m[(size_t)i*160 + threadIdx.x];
    __syncthreads();
    float xc = x[(size_t)i*CD + j], dx = dxprev[(size_t)i*CD + j];
    const float* tms[5] = {tmw, tmk, tmv, tmr, tmg};
    float* outs[5] = {xw, xk, xv, xr, xg};
    #pragma unroll
    for (int c = 0; c < 5; c++){
        float s = tms[c][j];
        const float* w2c = w2 + (size_t)c*32*CD + j;
        #pragma unroll
        for (int dm = 0; dm < 32; dm++) s += ms[c*32+dm] * w2c[(size_t)dm*CD];
        outs[c][(size_t)i*CD + j] = xc + dx*s;
    }
}

// ---------------- normalize k, stage v into X (head layout) ----------------
__global__ void k_knvx(const float* __restrict__ k, const float* __restrict__ v,
                       float* __restrict__ kn, float* __restrict__ X){
    int gw = (blockIdx.x*256 + threadIdx.x) >> 6;
    int lane = threadIdx.x & 63;
    if (gw >= CB*CH*CT) return;
    int t = gw % CT; int bh = gw / CT; int h = bh % CH; int b = bh / CH;
    size_t src = ((size_t)(b*CT + t))*CD + h*64 + lane;
    float kv = k[src];
    float ss = kv*kv;
    #pragma unroll
    for (int off = 32; off; off >>= 1) ss += __shfl_xor(ss, off);
    float nrm = fmaxf(sqrtf(ss), 1e-12f);
    size_t dst = ((size_t)bh*CT + t)*64 + lane;
    kn[dst] = kv / nrm;
    X[dst]  = v[src];
}

// ---------------- decay scan, fully coalesced ----------------
// block = 256 threads (4 waves) per (b,h); wave p handles t-rows p*16..p*16+15 of each chunk
__global__ __launch_bounds__(256) void k_scan2(const float* __restrict__ r, const float* __restrict__ k,
                        const float* __restrict__ w,
                        float* __restrict__ rf, float* __restrict__ kf,
                        float* __restrict__ rb, float* __restrict__ kb){
    __shared__ float parts[16][4][64];   // per chunk, wave, channel
    __shared__ float carr[16][64];       // exclusive chunk prefix per channel
    __shared__ float refs[2][64];
    int bh = blockIdx.x; int h = bh % CH; int b = bh / CH;
    int tid = threadIdx.x; int wid = tid >> 6; int ch = tid & 63;
    const float* wb = w + (size_t)b*CT*CD + h*64;
    // phase A: per-(chunk,wave) partial sums of wv = -exp(w)
    for (int tc = 0; tc < 16; tc++){
        float sum = 0.f;
        int tb = tc*64 + wid*16;
        for (int s = 0; s < 16; s++)
            sum -= expf(wb[(size_t)(tb+s)*CD + ch]);
        parts[tc][wid][ch] = sum;
    }
    __syncthreads();
    if (tid < 64){
        float run = 0.f;
        for (int tc = 0; tc < 16; tc++){
            carr[tc][tid] = run;
            run += parts[tc][0][tid] + parts[tc][1][tid] + parts[tc][2][tid] + parts[tc][3][tid];
        }
        float wv512 = -expf(wb[(size_t)512*CD + tid]);
        refs[0][tid] = carr[8][tid] + wv512;  // ref_f = cs(512)
        refs[1][tid] = carr[8][tid];          // ref_b = cs(512) - wv(512)
    }
    __syncthreads();
    const float* rbp = r + (size_t)b*CT*CD + h*64;
    const float* kbp = k + (size_t)b*CT*CD + h*64;
    size_t ob = (size_t)bh*CT*64;
    float ref_f = refs[0][ch], ref_b = refs[1][ch];
    for (int tc = 0; tc < 16; tc++){
        float run = carr[tc][ch];
        if (wid > 0) run += parts[tc][0][ch];
        if (wid > 1) run += parts[tc][1][ch];
        if (wid > 2) run += parts[tc][2][ch];
        int tb = tc*64 + wid*16;
        for (int s = 0; s < 16; s++){
            int t = tb + s;
            float wv = -expf(wb[(size_t)t*CD + ch]);
            run += wv;
            float csf = fminf(fmaxf(run - ref_f, -60.f), 60.f);
            float csb = fminf(fmaxf((run - wv) - ref_b, -60.f), 60.f);
            float rv = rbp[(size_t)t*CD + ch], kv = kbp[(size_t)t*CD + ch];
            float ef = expf(csf), enf = expf(-csf);
            float eb = expf(csb), enb = expf(-csb);
            rf[ob + (size_t)t*64 + ch] = rv * ef;
            kf[ob + (size_t)t*64 + ch] = kv * enf;
            rb[ob + (size_t)t*64 + ch] = rv * enb;
            kb[ob + (size_t)t*64 + ch] = kv * eb;
        }
    }
}

// ---------------- P(lower) = I + exp(clip(temp * kn knT)) ----------------
__global__ void k_gram(const float* __restrict__ kn, const float* __restrict__ lucid_temp,
                       float* __restrict__ P, int bh0){
    int t0 = blockIdx.y*64, s0 = blockIdx.x*64;
    if (t0 < s0) return;  // lower-triangular tiles only (upper never read)
    __shared__ float tA[64][65];
    __shared__ float tB[64][65];
    int lbh = blockIdx.z; int gbh = bh0 + lbh; int h = gbh % CH;
    int tid = threadIdx.x;
    LOAD_TILE(tA, kn + ((size_t)gbh*CT + t0)*64, 64);
    LOAD_TILE(tB, kn + ((size_t)gbh*CT + s0)*64, 64);
    __syncthreads();
    float tv = lucid_temp[h];
    tv = (tv > 20.f) ? tv : log1pf(expf(tv));
    int ty = (tid >> 4)*4, tx = (tid & 15)*4;
    float acc[4][4] = {};
    #pragma unroll
    for (int kk = 0; kk < 64; kk++){
        float a0[4], b0[4];
        #pragma unroll
        for (int i = 0; i < 4; i++){ a0[i] = tA[ty+i][kk]; b0[i] = tB[tx+i][kk]; }
        #pragma unroll
        for (int i = 0; i < 4; i++)
            #pragma unroll
            for (int j = 0; j < 4; j++) acc[i][j] += a0[i]*b0[j];
    }
    size_t pbase = (size_t)lbh*CT*CT;
    #pragma unroll
    for (int i = 0; i < 4; i++){
        int tt = t0+ty+i;
        float4 v;
        float g0 = fminf(fmaxf(tv*acc[i][0], -20.f), 20.f);
        float g1 = fminf(fmaxf(tv*acc[i][1], -20.f), 20.f);
        float g2 = fminf(fmaxf(tv*acc[i][2], -20.f), 20.f);
        float g3 = fminf(fmaxf(tv*acc[i][3], -20.f), 20.f);
        v.x = expf(g0) + ((tt == s0+tx+0) ? 1.f : 0.f);
        v.y = expf(g1) + ((tt == s0+tx+1) ? 1.f : 0.f);
        v.z = expf(g2) + ((tt == s0+tx+2) ? 1.f : 0.f);
        v.w = expf(g3) + ((tt == s0+tx+3) ? 1.f : 0.f);
        *(float4*)(P + pbase + (size_t)tt*CT + s0 + tx) = v;
    }
}

// ---------------- in-LDS 64x64 Cholesky + triangular inverse ----------------
// s: symmetric (lower valid) input; on exit s holds L (lower), inv holds L^-1.
__device__ __forceinline__ void potrf_inv(float (&s)[64][65], float (&inv)[64][65], int tid){
    for (int j = 0; j < 63; j++){
        __syncthreads();
        float invd = 1.f / fmaxf(s[j][j], 1e-20f);
        int n = 63 - j;
        for (int e = tid; e < n*n; e += 256){
            int ii = j+1 + e / n, cc = j+1 + e % n;
            s[ii][cc] -= s[ii][j]*s[cc][j]*invd;
        }
    }
    __syncthreads();
    for (int e = tid; e < 64*64; e += 256){
        int i2 = e >> 6, j2 = e & 63;
        if (i2 > j2) s[i2][j2] *= rsqrtf(fmaxf(s[j2][j2], 1e-20f));
    }
    __syncthreads();
    if (tid < 64) s[tid][tid] = sqrtf(fmaxf(s[tid][tid], 1e-20f));
    __syncthreads();
    if (tid < 64){
        int c = tid;
        for (int j = 0; j < c; j++) inv[j][c] = 0.f;
        for (int j = c; j < 64; j++){
            float sum = (j == c) ? 1.f : 0.f;
            for (int kk = c; kk < j; kk++) sum -= s[j][kk]*inv[kk][c];
            inv[j][c] = sum / s[j][j];
        }
    }
    __syncthreads();
}

__device__ __forceinline__ void potrf_writeout(float (&s)[64][65], float (&inv)[64][65], int tid,
                                               float* __restrict__ Pd, float* __restrict__ invp){
    for (int e = tid; e < 4096; e += 256){
        int r2 = e >> 6, c2 = e & 63;
        if (c2 <= r2) Pd[(size_t)r2*CT + c2] = s[r2][c2];
    }
    #pragma unroll
    for (int i_ = 0; i_ < 4; i_++){
        int rr_ = (tid>>4) + i_*16, cc_ = (tid&15)*4;
        float4 v_ = make_float4(inv[rr_][cc_], inv[rr_][cc_+1], inv[rr_][cc_+2], inv[rr_][cc_+3]);
        *(float4*)(invp + rr_*64 + cc_) = v_;
    }
}

// ---------------- factor first diagonal block ----------------
__global__ void k_potrf0(float* __restrict__ P, float* __restrict__ invL){
    __shared__ float s[64][65], inv[64][65];
    int bh = blockIdx.x; int tid = threadIdx.x;
    size_t base = (size_t)bh*CT*CT;
    LOAD_TILE(s, P + base, CT);
    __syncthreads();
    potrf_inv(s, inv, tid);
    potrf_writeout(s, inv, tid, P + base, invL + (size_t)bh*16*4096);
}

// ---------------- TRSM: panel = A21 @ invL11^T ----------------
__global__ void k_trsm(float* __restrict__ P, const float* __restrict__ invL, int jb){
    __shared__ float a[64][65];
    __shared__ float iv[64][65];
    int bh = blockIdx.y;
    int r0 = (jb+1)*NB + blockIdx.x*64;
    int j0 = jb*NB;
    size_t base = (size_t)bh*CT*CT;
    int tid = threadIdx.x;
    const float* invp = invL + ((size_t)bh*16 + jb)*4096;
    LOAD_TILE(a, P + base + (size_t)r0*CT + j0, CT);
    LOAD_TILE(iv, invp, 64);
    __syncthreads();
    int ty = (tid >> 4)*4, tx = (tid & 15)*4;
    float acc[4][4] = {};
    #pragma unroll
    for (int kk = 0; kk < 64; kk++){
        float a0[4], b0[4];
        #pragma unroll
        for (int i = 0; i < 4; i++){ a0[i] = a[ty+i][kk]; b0[i] = iv[tx+i][kk]; }
        #pragma unroll
        for (int i = 0; i < 4; i++)
            #pragma unroll
            for (int j = 0; j < 4; j++) acc[i][j] += a0[i]*b0[j];
    }
    #pragma unroll
    for (int i = 0; i < 4; i++)
        *(float4*)(P + base + (size_t)(r0+ty+i)*CT + j0 + tx) =
            make_float4(acc[i][0], acc[i][1], acc[i][2], acc[i][3]);
}

// ---------------- SYRK (lower tiles) + inline potrf of next diagonal ----------------
__global__ void k_syrkpo(float* __restrict__ P, float* __restrict__ invL, int jb){
    int ti = blockIdx.y, tj = blockIdx.x;
    if (tj > ti) return;
    int bh = blockIdx.z;
    int off = (jb+1)*NB;
    int r0 = off + ti*64, c0 = off + tj*64;
    int j0 = jb*NB;
    size_t base = (size_t)bh*CT*CT;
    __shared__ float La[64][65], Lb[64][65];
    int tid = threadIdx.x;
    LOAD_TILE(La, P + base + (size_t)r0*CT + j0, CT);
    LOAD_TILE(Lb, P + base + (size_t)c0*CT + j0, CT);
    __syncthreads();
    int ty = (tid >> 4)*4, tx = (tid & 15)*4;
    float acc[4][4] = {};
    #pragma unroll
    for (int kk = 0; kk < 64; kk++){
        float a0[4], b0[4];
        #pragma unroll
        for (int i = 0; i < 4; i++){ a0[i] = La[ty+i][kk]; b0[i] = Lb[tx+i][kk]; }
        #pragma unroll
        for (int i = 0; i < 4; i++)
            #pragma unroll
            for (int j = 0; j < 4; j++) acc[i][j] += a0[i]*b0[j];
    }
    if (!(ti == 0 && tj == 0)){
        #pragma unroll
        for (int i = 0; i < 4; i++){
            float4* p4 = (float4*)(P + base + (size_t)(r0+ty+i)*CT + c0 + tx);
            float4 v = *p4;
            v.x -= acc[i][0]; v.y -= acc[i][1]; v.z -= acc[i][2]; v.w -= acc[i][3];
            *p4 = v;
        }
    } else {
        // updated diagonal tile -> LDS, then factor in place
        __syncthreads();  // all reads of La/Lb done
        #pragma unroll
        for (int i = 0; i < 4; i++){
            float4 v = *(const float4*)(P + base + (size_t)(r0+ty+i)*CT + c0 + tx);
            La[ty+i][tx+0] = v.x - acc[i][0];
            La[ty+i][tx+1] = v.y - acc[i][1];
            La[ty+i][tx+2] = v.z - acc[i][2];
            La[ty+i][tx+3] = v.w - acc[i][3];
        }
        __syncthreads();
        potrf_inv(La, Lb, tid);
        potrf_writeout(La, Lb, tid, P + base + (size_t)off*CT + off,
                       invL + ((size_t)bh*16 + jb+1)*4096);
    }
}

// ---------------- fused block substitution (one launch per block-column) ----------------
// TRANS=0 fwd: Y = invL[jb] @ Xc[jb]; diag stores Yb[jb]; others Xc[ib] -= L[ib][jb] @ Y
// TRANS=1 bwd: Z = invL[jb]^T @ Yb[jb]; diag stores Xc[jb]; others Yb[ib] -= L[jb][ib]^T @ Z
template<int TRANS>
__global__ void k_solve(const float* __restrict__ P, const float* __restrict__ invL,
                        float* __restrict__ Xc, float* __restrict__ Yb, int bh0, int jb){
    __shared__ float A[64][65], B[64][65], C[64][65];
    int bh = blockIdx.y, tid = threadIdx.x;
    int ib = TRANS ? blockIdx.x : (jb + blockIdx.x);
    const float* invp = invL + ((size_t)bh*16 + jb)*4096;
    const float* src = (TRANS ? Yb : Xc) + ((size_t)(bh0+bh)*CT + jb*64)*64;
    LOAD_TILE(A, invp, 64);
    LOAD_TILE(B, src, 64);
    __syncthreads();
    int ty = (tid >> 4)*4, tx = (tid & 15)*4;
    float c4[4][4] = {};
    #pragma unroll
    for (int kk = 0; kk < 64; kk++){
        float a0[4], b0[4];
        #pragma unroll
        for (int i = 0; i < 4; i++){
            a0[i] = TRANS ? A[kk][ty+i] : A[ty+i][kk];
            b0[i] = B[kk][tx+i];
        }
        #pragma unroll
        for (int i = 0; i < 4; i++)
            #pragma unroll
            for (int j = 0; j < 4; j++) c4[i][j] += a0[i]*b0[j];
    }
    if (ib == jb){
        float* dst = (TRANS ? Xc : Yb) + ((size_t)(bh0+bh)*CT + jb*64)*64;
        #pragma unroll
        for (int i = 0; i < 4; i++)
            *(float4*)(dst + (size_t)(ty+i)*64 + tx) =
                make_float4(c4[i][0], c4[i][1], c4[i][2], c4[i][3]);
        return;
    }
    #pragma unroll
    for (int i = 0; i < 4; i++)
        #pragma unroll
        for (int j = 0; j < 4; j++) C[ty+i][tx+j] = c4[i][j];
    __syncthreads();
    const float* Lp = P + (size_t)bh*CT*CT + (TRANS ? ((size_t)(jb*64)*CT + ib*64)
                                                    : ((size_t)(ib*64)*CT + jb*64));
    LOAD_TILE(A, Lp, CT);
    __syncthreads();
    float u4[4][4] = {};
    #pragma unroll
    for (int kk = 0; kk < 64; kk++){
        float a0[4], b0[4];
        #pragma unroll
        for (int i = 0; i < 4; i++){
            a0[i] = TRANS ? A[kk][ty+i] : A[ty+i][kk];
            b0[i] = C[kk][tx+i];
        }
        #pragma unroll
        for (int i = 0; i < 4; i++)
            #pragma unroll
            for (int j = 0; j < 4; j++) u4[i][j] += a0[i]*b0[j];
    }
    float* dst = (TRANS ? Yb : Xc) + ((size_t)(bh0+bh)*CT + ib*64)*64;
    #pragma unroll
    for (int i = 0; i < 4; i++){
        float4* p4 = (float4*)(dst + (size_t)(ty+i)*64 + tx);
        float4 v = *p4;
        v.x -= u4[i][0]; v.y -= u4[i][1]; v.z -= u4[i][2]; v.w -= u4[i][3];
        *p4 = v;
    }
}

// ---------------- y = (tril(rf kf^T) + triu(rb kb^T,1)) @ Pv ----------------
__global__ void k_apv(const float* __restrict__ rf, const float* __restrict__ kf,
                      const float* __restrict__ rb, const float* __restrict__ kb,
                      const float* __restrict__ X, float* __restrict__ y){
    __shared__ float rs[64][65], ks[64][65], at[64][65];
    int bh = blockIdx.y, bx = blockIdx.x, t0 = bx*64;
    int tid = threadIdx.x;
    size_t hb = (size_t)bh*CT*64;
    int ty = (tid >> 4)*4, tx = (tid & 15)*4;
    float yacc[4][4] = {};
    for (int st = 0; st < 16; st++){
        int s0 = st*64;
        bool dg = (st == bx);
        const float* rp = (st > bx) ? rb : rf;
        const float* kp = (st > bx) ? kb : kf;
        LOAD_TILE(rs, rp + hb + (size_t)t0*64, 64);
        LOAD_TILE(ks, kp + hb + (size_t)s0*64, 64);
        __syncthreads();
        float a4[4][4] = {};
        #pragma unroll
        for (int kk = 0; kk < 64; kk++){
            float a0[4], b0[4];
            #pragma unroll
            for (int i = 0; i < 4; i++){ a0[i] = rs[ty+i][kk]; b0[i] = ks[tx+i][kk]; }
            #pragma unroll
            for (int i = 0; i < 4; i++)
                #pragma unroll
                for (int j = 0; j < 4; j++) a4[i][j] += a0[i]*b0[j];
        }
        #pragma unroll
        for (int i = 0; i < 4; i++)
            #pragma unroll
            for (int j = 0; j < 4; j++)
                at[ty+i][tx+j] = (!dg || (ty+i) >= (tx+j)) ? a4[i][j] : 0.f;
        __syncthreads();
        if (dg){
            LOAD_TILE(rs, rb + hb + (size_t)t0*64, 64);
            LOAD_TILE(ks, kb + hb + (size_t)s0*64, 64);
            __syncthreads();
            float b4[4][4] = {};
            #pragma unroll
            for (int kk = 0; kk < 64; kk++){
                float a0[4], b0[4];
                #pragma unroll
                for (int i = 0; i < 4; i++){ a0[i] = rs[ty+i][kk]; b0[i] = ks[tx+i][kk]; }
                #pragma unroll
                for (int i = 0; i < 4; i++)
                    #pragma unroll
                    for (int j = 0; j < 4; j++) b4[i][j] += a0[i]*b0[j];
            }
            #pragma unroll
            for (int i = 0; i < 4; i++)
                #pragma unroll
                for (int j = 0; j < 4; j++)
                    if ((ty+i) < (tx+j)) at[ty+i][tx+j] = b4[i][j];
            __syncthreads();
        }
        LOAD_TILE(rs, X + hb + (size_t)s0*64, 64);
        __syncthreads();
        #pragma unroll 8
        for (int s = 0; s < 64; s++){
            float a0[4], b0[4];
            #pragma unroll
            for (int i = 0; i < 4; i++){ a0[i] = at[ty+i][s]; b0[i] = rs[s][tx+i]; }
            #pragma unroll
            for (int i = 0; i < 4; i++)
                #pragma unroll
                for (int j = 0; j < 4; j++) yacc[i][j] += a0[i]*b0[j];
        }
        __syncthreads();
    }
    #pragma unroll
    for (int i = 0; i < 4; i++)
        *(float4*)(y + hb + (size_t)(t0+ty+i)*64 + tx) =
            make_float4(yacc[i][0], yacc[i][1], yacc[i][2], yacc[i][3]);
}

// ---------------- GroupNorm + gate ----------------
__global__ void k_gn(const float* __restrict__ y, const float* __restrict__ g,
                     const float* __restrict__ lnw, const float* __restrict__ lnb,
                     float* __restrict__ z){
    int gw = (blockIdx.x*256 + threadIdx.x) >> 6;
    int lane = threadIdx.x & 63;
    if (gw >= CB*CT*CH) return;
    int h = gw % CH; int bt = gw / CH;
    int b = bt / CT, t = bt % CT;
    int bh = b*CH + h;
    float yv = y[((size_t)bh*CT + t)*64 + lane];
    float s1 = yv, s2 = yv*yv;
    #pragma unroll
    for (int off = 32; off; off >>= 1){ s1 += __shfl_xor(s1, off); s2 += __shfl_xor(s2, off); }
    float mu = s1 * (1.f/64.f);
    float var = s2 * (1.f/64.f) - mu*mu;
    float inv = rsqrtf(var + 6.4e-4f);
    int d = h*64 + lane;
    float yn = (yv - mu)*inv*lnw[d] + lnb[d];
    z[(size_t)bt*CD + d] = yn * g[(size_t)bt*CD + d];
}

extern "C" void kernel_launch(void* const* d_in, const int* in_sizes, int n_in,
                              void* d_out, int out_size, void* d_ws, size_t ws_size,
                              hipStream_t stream){
    const float* x          = (const float*)d_in[0];
    const float* tmx        = (const float*)d_in[1];
    const float* tmw        = (const float*)d_in[2];
    const float* tmk        = (const float*)d_in[3];
    const float* tmv        = (const float*)d_in[4];
    const float* tmr        = (const float*)d_in[5];
    const float* tmg        = (const float*)d_in[6];
    const float* maa_w1     = (const float*)d_in[7];
    const float* maa_w2     = (const float*)d_in[8];
    const float* time_decay = (const float*)d_in[9];
    const float* decay_w1   = (const float*)d_in[10];
    const float* decay_w2   = (const float*)d_in[11];
    const float* lucid_temp = (const float*)d_in[12];
    const float* Wr         = (const float*)d_in[13];
    const float* Wk         = (const float*)d_in[14];
    const float* Wv         = (const float*)d_in[15];
    const float* Wg         = (const float*)d_in[16];
    const float* Wo         = (const float*)d_in[17];
    const float* lnw        = (const float*)d_in[18];
    const float* lnb        = (const float*)d_in[19];
    float* out = (float*)d_out;
    float* ws  = (float*)d_ws;

    const size_t S = (size_t)CB*CT*CD;
    float* b0 = ws;          // dxprev -> wbuf -> Yb
    float* b1 = ws + 1*S;    // xxx -> xw -> rf
    float* b2 = ws + 2*S;    // xk -> kf
    float* b3 = ws + 3*S;    // xv -> rb
    float* b4 = ws + 4*S;    // xr -> kn
    float* b5 = ws + 5*S;    // xg -> X (v -> Pv)
    float* b6 = ws + 6*S;    // rbuf -> y
    float* b7 = ws + 7*S;    // kbuf -> z
    float* b8 = ws + 8*S;    // vbuf -> kb
    float* b9 = ws + 9*S;    // gbuf
    float* mbuf = ws + 10*S;
    const size_t MB_F = 4096*160;
    size_t base_f = 10*S + MB_F;

    const size_t per_bh = (size_t)CT*CT + 16*NB*NB;
    size_t avail = ws_size / sizeof(float);
    int G = 1;
    if (avail > base_f + per_bh){
        size_t g = (avail - base_f) / per_bh;
        G = (g >= CBH) ? CBH : (int)g;
        if (G < 1) G = 1;
    }
    float* P    = ws + base_f;
    float* invL = P + (size_t)G*CT*CT;

    float* dxprev = b0; float* xxx = b1;
    float* xw = b1; float* xk = b2; float* xv = b3; float* xr = b4; float* xg = b5;
    float* rbuf = b6; float* kbuf = b7; float* vbuf = b8; float* gbuf = b9; float* wbuf = b0;
    float* kn = b4; float* X = b5;
    float* rf = b1; float* kf = b2; float* rb = b3; float* kb = b8;
    float* Yb = b0;
    float* ybuf = b6; float* zbuf = b7;

    k_shift<<<dim3((CB*CT*CD + 255)/256), 256, 0, stream>>>(x, tmx, dxprev, xxx);
    k_gemm<1><<<dim3(3, 32), 256, 0, stream>>>(xxx, maa_w1, nullptr, mbuf, 4096, 160, 768);
    k_mix5<<<dim3(3, 4096), 256, 0, stream>>>(x, dxprev, mbuf, tmw, tmk, tmv, tmr, tmg,
                                              maa_w2, xw, xk, xv, xr, xg);
    k_gemm<0><<<dim3(12, 32), 256, 0, stream>>>(xr, Wr, nullptr, rbuf, 4096, 768, 768);
    k_gemm<0><<<dim3(12, 32), 256, 0, stream>>>(xk, Wk, nullptr, kbuf, 4096, 768, 768);
    k_gemm<0><<<dim3(12, 32), 256, 0, stream>>>(xv, Wv, nullptr, vbuf, 4096, 768, 768);
    k_gemm<2><<<dim3(12, 32), 256, 0, stream>>>(xg, Wg, nullptr, gbuf, 4096, 768, 768);
    k_gemm<1><<<dim3(1, 32), 256, 0, stream>>>(xw, decay_w1, nullptr, mbuf, 4096, 64, 768);
    k_gemm<3><<<dim3(12, 32), 256, 0, stream>>>(mbuf, decay_w2, time_decay, wbuf, 4096, 768, 64);

    k_knvx<<<dim3((CB*CH*CT*64)/256), 256, 0, stream>>>(kbuf, vbuf, kn, X);
    k_scan2<<<dim3(CBH), 256, 0, stream>>>(rbuf, kbuf, wbuf, rf, kf, rb, kb);

    for (int bh0 = 0; bh0 < CBH; bh0 += G){
        int Gc = (CBH - bh0 < G) ? (CBH - bh0) : G;
        k_gram<<<dim3(16, 16, Gc), 256, 0, stream>>>(kn, lucid_temp, P, bh0);
        k_potrf0<<<dim3(Gc), 256, 0, stream>>>(P, invL);
        for (int jb = 0; jb < 15; jb++){
            int nt = 15 - jb;
            k_trsm<<<dim3(nt, Gc), 256, 0, stream>>>(P, invL, jb);
            k_syrkpo<<<dim3(nt, nt, Gc), 256, 0, stream>>>(P, invL, jb);
        }
        for (int jb = 0; jb < 16; jb++)
            k_solve<0><<<dim3(16-jb, Gc), 256, 0, stream>>>(P, invL, X, Yb, bh0, jb);
        for (int jb = 15; jb >= 0; jb--)
            k_solve<1><<<dim3(jb+1, Gc), 256, 0, stream>>>(P, invL, X, Yb, bh0, jb);
    }

    k_apv<<<dim3(16, CBH), 256, 0, stream>>>(rf, kf, rb, kb, X, ybuf);
    k_gn<<<dim3((CB*CT*CH*64)/256), 256, 0, stream>>>(ybuf, gbuf, lnw, lnb, zbuf);
    k_gemm<0><<<dim3(12, 32), 256, 0, stream>>>(zbuf, Wo, nullptr, out, 4096, 768, 768);
}

// Round 5
// 5930.162 us; speedup vs baseline: 5.2512x; 1.4551x over previous
//
#include <hip/hip_runtime.h>
#include <math.h>

#define CB 4
#define CT 1024
#define CD 768
#define CH 12
#define CK 64
#define CBH (CB*CH)
#define NB 64

// cooperative 64x64 tile load: global (row-major, given stride) -> LDS [64][65]
#define LOAD_TILE(dst, src, stride) { \
    _Pragma("unroll") \
    for (int i_ = 0; i_ < 4; i_++){ \
        int rr_ = (tid>>4) + i_*16, cc_ = (tid&15)*4; \
        float4 v_ = *(const float4*)((src) + (size_t)rr_*(stride) + cc_); \
        dst[rr_][cc_+0]=v_.x; dst[rr_][cc_+1]=v_.y; dst[rr_][cc_+2]=v_.z; dst[rr_][cc_+3]=v_.w; \
    } }

// ---------------- elementwise: token shift + xxx ----------------
__global__ void k_shift(const float* __restrict__ x, const float* __restrict__ tmx,
                        float* __restrict__ dxprev, float* __restrict__ xxx){
    int idx = blockIdx.x*256 + threadIdx.x;
    if (idx >= CB*CT*CD) return;
    int d = idx % CD;
    int bt = idx / CD;
    int t = bt % CT;
    float xc = x[idx];
    float xl = (t > 0)      ? x[idx - CD] : 0.f;
    float xr = (t < CT-1)   ? x[idx + CD] : 0.f;
    float dx = 0.5f*(xl + xr) - xc;
    dxprev[idx] = dx;
    xxx[idx] = xc + dx * tmx[d];
}

// ---------------- generic tiled fp32 GEMM ----------------
template<int MODE>
__global__ void k_gemm(const float* __restrict__ A, const float* __restrict__ Bm,
                       const float* __restrict__ bias, float* __restrict__ C,
                       int M, int N, int Kd){
    __shared__ float As[16][128];
    __shared__ float Bs[16][64];
    int tid = threadIdx.x;
    int m0 = blockIdx.y * 128, n0 = blockIdx.x * 64;
    int tn = (tid & 15) * 4;
    int tm = (tid >> 4) * 8;
    float acc[8][4] = {};
    for (int k0 = 0; k0 < Kd; k0 += 16){
        #pragma unroll
        for (int i = 0; i < 8; i++){
            int e = tid + i*256;
            int r = e >> 4, c = e & 15;
            As[c][r] = A[(size_t)(m0+r)*Kd + k0 + c];
        }
        #pragma unroll
        for (int i = 0; i < 4; i++){
            int e = tid + i*256;
            int r = e >> 6, c = e & 63;
            float bv = 0.f;
            if (n0 + c < N) bv = Bm[(size_t)(k0+r)*N + n0 + c];
            Bs[r][c] = bv;
        }
        __syncthreads();
        #pragma unroll
        for (int kk = 0; kk < 16; kk++){
            float a0[8], b0[4];
            #pragma unroll
            for (int i = 0; i < 8; i++) a0[i] = As[kk][tm+i];
            #pragma unroll
            for (int j = 0; j < 4; j++) b0[j] = Bs[kk][tn+j];
            #pragma unroll
            for (int i = 0; i < 8; i++)
                #pragma unroll
                for (int j = 0; j < 4; j++) acc[i][j] += a0[i]*b0[j];
        }
        __syncthreads();
    }
    #pragma unroll
    for (int i = 0; i < 8; i++)
        #pragma unroll
        for (int j = 0; j < 4; j++){
            int mm = m0 + tm + i, nn = n0 + tn + j;
            if (nn < N){
                float v = acc[i][j];
                if (MODE == 1) v = tanhf(v);
                else if (MODE == 2) v = v / (1.f + expf(-v));
                else if (MODE == 3) v += bias[nn];
                C[(size_t)mm*N + nn] = v;
            }
        }
}

// ---------------- 5-way low-rank mix ----------------
__global__ void k_mix5(const float* __restrict__ x, const float* __restrict__ dxprev,
                       const float* __restrict__ m,
                       const float* __restrict__ tmw, const float* __restrict__ tmk,
                       const float* __restrict__ tmv, const float* __restrict__ tmr,
                       const float* __restrict__ tmg, const float* __restrict__ w2,
                       float* __restrict__ xw, float* __restrict__ xk, float* __restrict__ xv,
                       float* __restrict__ xr, float* __restrict__ xg){
    __shared__ float ms[160];
    int i = blockIdx.y;
    int j = blockIdx.x*256 + threadIdx.x;
    if (threadIdx.x < 160) ms[threadIdx.x] = m[(size_t)i*160 + threadIdx.x];
    __syncthreads();
    float xc = x[(size_t)i*CD + j], dx = dxprev[(size_t)i*CD + j];
    const float* tms[5] = {tmw, tmk, tmv, tmr, tmg};
    float* outs[5] = {xw, xk, xv, xr, xg};
    #pragma unroll
    for (int c = 0; c < 5; c++){
        float s = tms[c][j];
        const float* w2c = w2 + (size_t)c*32*CD + j;
        #pragma unroll
        for (int dm = 0; dm < 32; dm++) s += ms[c*32+dm] * w2c[(size_t)dm*CD];
        outs[c][(size_t)i*CD + j] = xc + dx*s;
    }
}

// ---------------- normalize k, stage v into X (head layout) ----------------
__global__ void k_knvx(const float* __restrict__ k, const float* __restrict__ v,
                       float* __restrict__ kn, float* __restrict__ X){
    int gw = (blockIdx.x*256 + threadIdx.x) >> 6;
    int lane = threadIdx.x & 63;
    if (gw >= CB*CH*CT) return;
    int t = gw % CT; int bh = gw / CT; int h = bh % CH; int b = bh / CH;
    size_t src = ((size_t)(b*CT + t))*CD + h*64 + lane;
    float kv = k[src];
    float ss = kv*kv;
    #pragma unroll
    for (int off = 32; off; off >>= 1) ss += __shfl_xor(ss, off);
    float nrm = fmaxf(sqrtf(ss), 1e-12f);
    size_t dst = ((size_t)bh*CT + t)*64 + lane;
    kn[dst] = kv / nrm;
    X[dst]  = v[src];
}

// ---------------- decay scan, fully coalesced ----------------
__global__ __launch_bounds__(256) void k_scan2(const float* __restrict__ r, const float* __restrict__ k,
                        const float* __restrict__ w,
                        float* __restrict__ rf, float* __restrict__ kf,
                        float* __restrict__ rb, float* __restrict__ kb){
    __shared__ float parts[16][4][64];
    __shared__ float carr[16][64];
    __shared__ float refs[2][64];
    int bh = blockIdx.x; int h = bh % CH; int b = bh / CH;
    int tid = threadIdx.x; int wid = tid >> 6; int ch = tid & 63;
    const float* wb = w + (size_t)b*CT*CD + h*64;
    for (int tc = 0; tc < 16; tc++){
        float sum = 0.f;
        int tb = tc*64 + wid*16;
        for (int s = 0; s < 16; s++)
            sum -= expf(wb[(size_t)(tb+s)*CD + ch]);
        parts[tc][wid][ch] = sum;
    }
    __syncthreads();
    if (tid < 64){
        float run = 0.f;
        for (int tc = 0; tc < 16; tc++){
            carr[tc][tid] = run;
            run += parts[tc][0][tid] + parts[tc][1][tid] + parts[tc][2][tid] + parts[tc][3][tid];
        }
        float wv512 = -expf(wb[(size_t)512*CD + tid]);
        refs[0][tid] = carr[8][tid] + wv512;
        refs[1][tid] = carr[8][tid];
    }
    __syncthreads();
    const float* rbp = r + (size_t)b*CT*CD + h*64;
    const float* kbp = k + (size_t)b*CT*CD + h*64;
    size_t ob = (size_t)bh*CT*64;
    float ref_f = refs[0][ch], ref_b = refs[1][ch];
    for (int tc = 0; tc < 16; tc++){
        float run = carr[tc][ch];
        if (wid > 0) run += parts[tc][0][ch];
        if (wid > 1) run += parts[tc][1][ch];
        if (wid > 2) run += parts[tc][2][ch];
        int tb = tc*64 + wid*16;
        for (int s = 0; s < 16; s++){
            int t = tb + s;
            float wv = -expf(wb[(size_t)t*CD + ch]);
            run += wv;
            float csf = fminf(fmaxf(run - ref_f, -60.f), 60.f);
            float csb = fminf(fmaxf((run - wv) - ref_b, -60.f), 60.f);
            float rv = rbp[(size_t)t*CD + ch], kv = kbp[(size_t)t*CD + ch];
            rf[ob + (size_t)t*64 + ch] = rv * expf(csf);
            kf[ob + (size_t)t*64 + ch] = kv * expf(-csf);
            rb[ob + (size_t)t*64 + ch] = rv * expf(-csb);
            kb[ob + (size_t)t*64 + ch] = kv * expf(csb);
        }
    }
}

// ---------------- P(lower) = I + exp(clip(temp * kn knT)) ----------------
__global__ void k_gram(const float* __restrict__ kn, const float* __restrict__ lucid_temp,
                       float* __restrict__ P, int bh0){
    int t0 = blockIdx.y*64, s0 = blockIdx.x*64;
    if (t0 < s0) return;
    __shared__ float tA[64][65];
    __shared__ float tB[64][65];
    int lbh = blockIdx.z; int gbh = bh0 + lbh; int h = gbh % CH;
    int tid = threadIdx.x;
    LOAD_TILE(tA, kn + ((size_t)gbh*CT + t0)*64, 64);
    LOAD_TILE(tB, kn + ((size_t)gbh*CT + s0)*64, 64);
    __syncthreads();
    float tv = lucid_temp[h];
    tv = (tv > 20.f) ? tv : log1pf(expf(tv));
    int ty = (tid >> 4)*4, tx = (tid & 15)*4;
    float acc[4][4] = {};
    #pragma unroll
    for (int kk = 0; kk < 64; kk++){
        float a0[4], b0[4];
        #pragma unroll
        for (int i = 0; i < 4; i++){ a0[i] = tA[ty+i][kk]; b0[i] = tB[tx+i][kk]; }
        #pragma unroll
        for (int i = 0; i < 4; i++)
            #pragma unroll
            for (int j = 0; j < 4; j++) acc[i][j] += a0[i]*b0[j];
    }
    size_t pbase = (size_t)lbh*CT*CT;
    #pragma unroll
    for (int i = 0; i < 4; i++){
        int tt = t0+ty+i;
        float4 v;
        float g0 = fminf(fmaxf(tv*acc[i][0], -20.f), 20.f);
        float g1 = fminf(fmaxf(tv*acc[i][1], -20.f), 20.f);
        float g2 = fminf(fmaxf(tv*acc[i][2], -20.f), 20.f);
        float g3 = fminf(fmaxf(tv*acc[i][3], -20.f), 20.f);
        v.x = expf(g0) + ((tt == s0+tx+0) ? 1.f : 0.f);
        v.y = expf(g1) + ((tt == s0+tx+1) ? 1.f : 0.f);
        v.z = expf(g2) + ((tt == s0+tx+2) ? 1.f : 0.f);
        v.w = expf(g3) + ((tt == s0+tx+3) ? 1.f : 0.f);
        *(float4*)(P + pbase + (size_t)tt*CT + s0 + tx) = v;
    }
}

// ---------------- in-LDS 64x64 Cholesky + triangular inverse ----------------
__device__ __forceinline__ void potrf_inv(float (&s)[64][65], float (&inv)[64][65], int tid){
    for (int j = 0; j < 63; j++){
        __syncthreads();
        float invd = 1.f / fmaxf(s[j][j], 1e-20f);
        int n = 63 - j;
        for (int e = tid; e < n*n; e += 256){
            int ii = j+1 + e / n, cc = j+1 + e % n;
            s[ii][cc] -= s[ii][j]*s[cc][j]*invd;
        }
    }
    __syncthreads();
    for (int e = tid; e < 64*64; e += 256){
        int i2 = e >> 6, j2 = e & 63;
        if (i2 > j2) s[i2][j2] *= rsqrtf(fmaxf(s[j2][j2], 1e-20f));
    }
    __syncthreads();
    if (tid < 64) s[tid][tid] = sqrtf(fmaxf(s[tid][tid], 1e-20f));
    __syncthreads();
    if (tid < 64){
        int c = tid;
        for (int j = 0; j < c; j++) inv[j][c] = 0.f;
        for (int j = c; j < 64; j++){
            float sum = (j == c) ? 1.f : 0.f;
            for (int kk = c; kk < j; kk++) sum -= s[j][kk]*inv[kk][c];
            inv[j][c] = sum / s[j][j];
        }
    }
    __syncthreads();
}

__device__ __forceinline__ void potrf_writeout(float (&s)[64][65], float (&inv)[64][65], int tid,
                                               float* __restrict__ Pd, float* __restrict__ invp){
    for (int e = tid; e < 4096; e += 256){
        int r2 = e >> 6, c2 = e & 63;
        if (c2 <= r2) Pd[(size_t)r2*CT + c2] = s[r2][c2];
    }
    #pragma unroll
    for (int i_ = 0; i_ < 4; i_++){
        int rr_ = (tid>>4) + i_*16, cc_ = (tid&15)*4;
        float4 v_ = make_float4(inv[rr_][cc_], inv[rr_][cc_+1], inv[rr_][cc_+2], inv[rr_][cc_+3]);
        *(float4*)(invp + rr_*64 + cc_) = v_;
    }
}

__global__ void k_potrf0(float* __restrict__ P, float* __restrict__ invL){
    __shared__ float s[64][65], inv[64][65];
    int bh = blockIdx.x; int tid = threadIdx.x;
    size_t base = (size_t)bh*CT*CT;
    LOAD_TILE(s, P + base, CT);
    __syncthreads();
    potrf_inv(s, inv, tid);
    potrf_writeout(s, inv, tid, P + base, invL + (size_t)bh*16*4096);
}

// ---------------- TRSM: panel = A21 @ invL11^T ----------------
__global__ void k_trsm(float* __restrict__ P, const float* __restrict__ invL, int jb){
    __shared__ float a[64][65];
    __shared__ float iv[64][65];
    int bh = blockIdx.y;
    int r0 = (jb+1)*NB + blockIdx.x*64;
    int j0 = jb*NB;
    size_t base = (size_t)bh*CT*CT;
    int tid = threadIdx.x;
    const float* invp = invL + ((size_t)bh*16 + jb)*4096;
    LOAD_TILE(a, P + base + (size_t)r0*CT + j0, CT);
    LOAD_TILE(iv, invp, 64);
    __syncthreads();
    int ty = (tid >> 4)*4, tx = (tid & 15)*4;
    float acc[4][4] = {};
    #pragma unroll
    for (int kk = 0; kk < 64; kk++){
        float a0[4], b0[4];
        #pragma unroll
        for (int i = 0; i < 4; i++){ a0[i] = a[ty+i][kk]; b0[i] = iv[tx+i][kk]; }
        #pragma unroll
        for (int i = 0; i < 4; i++)
            #pragma unroll
            for (int j = 0; j < 4; j++) acc[i][j] += a0[i]*b0[j];
    }
    #pragma unroll
    for (int i = 0; i < 4; i++)
        *(float4*)(P + base + (size_t)(r0+ty+i)*CT + j0 + tx) =
            make_float4(acc[i][0], acc[i][1], acc[i][2], acc[i][3]);
}

// ---------------- SYRK (lower tiles) + inline potrf of next diagonal ----------------
__global__ void k_syrkpo(float* __restrict__ P, float* __restrict__ invL, int jb){
    int ti = blockIdx.y, tj = blockIdx.x;
    if (tj > ti) return;
    int bh = blockIdx.z;
    int off = (jb+1)*NB;
    int r0 = off + ti*64, c0 = off + tj*64;
    int j0 = jb*NB;
    size_t base = (size_t)bh*CT*CT;
    __shared__ float La[64][65], Lb[64][65];
    int tid = threadIdx.x;
    LOAD_TILE(La, P + base + (size_t)r0*CT + j0, CT);
    LOAD_TILE(Lb, P + base + (size_t)c0*CT + j0, CT);
    __syncthreads();
    int ty = (tid >> 4)*4, tx = (tid & 15)*4;
    float acc[4][4] = {};
    #pragma unroll
    for (int kk = 0; kk < 64; kk++){
        float a0[4], b0[4];
        #pragma unroll
        for (int i = 0; i < 4; i++){ a0[i] = La[ty+i][kk]; b0[i] = Lb[tx+i][kk]; }
        #pragma unroll
        for (int i = 0; i < 4; i++)
            #pragma unroll
            for (int j = 0; j < 4; j++) acc[i][j] += a0[i]*b0[j];
    }
    if (!(ti == 0 && tj == 0)){
        #pragma unroll
        for (int i = 0; i < 4; i++){
            float4* p4 = (float4*)(P + base + (size_t)(r0+ty+i)*CT + c0 + tx);
            float4 v = *p4;
            v.x -= acc[i][0]; v.y -= acc[i][1]; v.z -= acc[i][2]; v.w -= acc[i][3];
            *p4 = v;
        }
    } else {
        __syncthreads();
        #pragma unroll
        for (int i = 0; i < 4; i++){
            float4 v = *(const float4*)(P + base + (size_t)(r0+ty+i)*CT + c0 + tx);
            La[ty+i][tx+0] = v.x - acc[i][0];
            La[ty+i][tx+1] = v.y - acc[i][1];
            La[ty+i][tx+2] = v.z - acc[i][2];
            La[ty+i][tx+3] = v.w - acc[i][3];
        }
        __syncthreads();
        potrf_inv(La, Lb, tid);
        potrf_writeout(La, Lb, tid, P + base + (size_t)off*CT + off,
                       invL + ((size_t)bh*16 + jb+1)*4096);
    }
}

// ---------------- fused block substitution ----------------
template<int TRANS>
__global__ void k_solve(const float* __restrict__ P, const float* __restrict__ invL,
                        float* __restrict__ Xc, float* __restrict__ Yb, int bh0, int jb){
    __shared__ float A[64][65], B[64][65], C[64][65];
    int bh = blockIdx.y, tid = threadIdx.x;
    int ib = TRANS ? blockIdx.x : (jb + blockIdx.x);
    const float* invp = invL + ((size_t)bh*16 + jb)*4096;
    const float* src = (TRANS ? Yb : Xc) + ((size_t)(bh0+bh)*CT + jb*64)*64;
    LOAD_TILE(A, invp, 64);
    LOAD_TILE(B, src, 64);
    __syncthreads();
    int ty = (tid >> 4)*4, tx = (tid & 15)*4;
    float c4[4][4] = {};
    #pragma unroll
    for (int kk = 0; kk < 64; kk++){
        float a0[4], b0[4];
        #pragma unroll
        for (int i = 0; i < 4; i++){
            a0[i] = TRANS ? A[kk][ty+i] : A[ty+i][kk];
            b0[i] = B[kk][tx+i];
        }
        #pragma unroll
        for (int i = 0; i < 4; i++)
            #pragma unroll
            for (int j = 0; j < 4; j++) c4[i][j] += a0[i]*b0[j];
    }
    if (ib == jb){
        float* dst = (TRANS ? Xc : Yb) + ((size_t)(bh0+bh)*CT + jb*64)*64;
        #pragma unroll
        for (int i = 0; i < 4; i++)
            *(float4*)(dst + (size_t)(ty+i)*64 + tx) =
                make_float4(c4[i][0], c4[i][1], c4[i][2], c4[i][3]);
        return;
    }
    #pragma unroll
    for (int i = 0; i < 4; i++)
        #pragma unroll
        for (int j = 0; j < 4; j++) C[ty+i][tx+j] = c4[i][j];
    __syncthreads();
    const float* Lp = P + (size_t)bh*CT*CT + (TRANS ? ((size_t)(jb*64)*CT + ib*64)
                                                    : ((size_t)(ib*64)*CT + jb*64));
    LOAD_TILE(A, Lp, CT);
    __syncthreads();
    float u4[4][4] = {};
    #pragma unroll
    for (int kk = 0; kk < 64; kk++){
        float a0[4], b0[4];
        #pragma unroll
        for (int i = 0; i < 4; i++){
            a0[i] = TRANS ? A[kk][ty+i] : A[ty+i][kk];
            b0[i] = C[kk][tx+i];
        }
        #pragma unroll
        for (int i = 0; i < 4; i++)
            #pragma unroll
            for (int j = 0; j < 4; j++) u4[i][j] += a0[i]*b0[j];
    }
    float* dst = (TRANS ? Yb : Xc) + ((size_t)(bh0+bh)*CT + ib*64)*64;
    #pragma unroll
    for (int i = 0; i < 4; i++){
        float4* p4 = (float4*)(dst + (size_t)(ty+i)*64 + tx);
        float4 v = *p4;
        v.x -= u4[i][0]; v.y -= u4[i][1]; v.z -= u4[i][2]; v.w -= u4[i][3];
        *p4 = v;
    }
}

// ---------------- per-chunk outer products: U_f = kf_c^T @ Pv_c, U_b = kb_c^T @ Pv_c ----------------
__global__ void k_outer(const float* __restrict__ kf, const float* __restrict__ kb,
                        const float* __restrict__ X,
                        float* __restrict__ Sf, float* __restrict__ Sb){
    __shared__ float kfs[64][65], kbs[64][65], pvs[64][65];
    int c = blockIdx.x, bh = blockIdx.y, tid = threadIdx.x;
    size_t hb = (size_t)bh*CT*64 + (size_t)c*64*64;
    LOAD_TILE(kfs, kf + hb, 64);
    LOAD_TILE(kbs, kb + hb, 64);
    LOAD_TILE(pvs, X + hb, 64);
    __syncthreads();
    int ty = (tid >> 4)*4, tx = (tid & 15)*4;
    float af[4][4] = {}, ab[4][4] = {};
    #pragma unroll
    for (int kk = 0; kk < 64; kk++){
        float f0[4], g0[4], b0[4];
        #pragma unroll
        for (int i = 0; i < 4; i++){
            f0[i] = kfs[kk][ty+i];
            g0[i] = kbs[kk][ty+i];
            b0[i] = pvs[kk][tx+i];
        }
        #pragma unroll
        for (int i = 0; i < 4; i++)
            #pragma unroll
            for (int j = 0; j < 4; j++){
                af[i][j] += f0[i]*b0[j];
                ab[i][j] += g0[i]*b0[j];
            }
    }
    size_t sb = ((size_t)bh*16 + c)*4096;
    #pragma unroll
    for (int i = 0; i < 4; i++){
        *(float4*)(Sf + sb + (size_t)(ty+i)*64 + tx) = make_float4(af[i][0], af[i][1], af[i][2], af[i][3]);
        *(float4*)(Sb + sb + (size_t)(ty+i)*64 + tx) = make_float4(ab[i][0], ab[i][1], ab[i][2], ab[i][3]);
    }
}

// ---------------- in-place chunk-state cumsum: Sf -> exclusive fwd, Sb -> exclusive bwd ----------------
__global__ void k_cumsum(float* __restrict__ Sf, float* __restrict__ Sb){
    int bh = blockIdx.x, tid = threadIdx.x;
    size_t base = (size_t)bh*16*4096;
    #pragma unroll
    for (int i = 0; i < 16; i++){
        int e = tid + i*256;
        float run = 0.f;
        for (int c = 0; c < 16; c++){
            float* p = Sf + base + (size_t)c*4096 + e;
            float t = *p; *p = run; run += t;
        }
        run = 0.f;
        for (int c = 15; c >= 0; c--){
            float* p = Sb + base + (size_t)c*4096 + e;
            float t = *p; *p = run; run += t;
        }
    }
}

// ---------------- per-chunk y: masked diag + state GEMMs ----------------
__global__ void k_apv2(const float* __restrict__ rf, const float* __restrict__ kf,
                       const float* __restrict__ rb, const float* __restrict__ kb,
                       const float* __restrict__ X,
                       const float* __restrict__ Sf, const float* __restrict__ Sb,
                       float* __restrict__ y){
    __shared__ float rs[64][65], ks[64][65], at[64][65];
    int c = blockIdx.x, bh = blockIdx.y, tid = threadIdx.x;
    size_t hb = (size_t)bh*CT*64 + (size_t)c*64*64;
    size_t sb = ((size_t)bh*16 + c)*4096;
    int ty = (tid >> 4)*4, tx = (tid & 15)*4;
    // diag fwd product
    LOAD_TILE(rs, rf + hb, 64);
    LOAD_TILE(ks, kf + hb, 64);
    __syncthreads();
    float a4[4][4] = {};
    #pragma unroll
    for (int kk = 0; kk < 64; kk++){
        float a0[4], b0[4];
        #pragma unroll
        for (int i = 0; i < 4; i++){ a0[i] = rs[ty+i][kk]; b0[i] = ks[tx+i][kk]; }
        #pragma unroll
        for (int i = 0; i < 4; i++)
            #pragma unroll
            for (int j = 0; j < 4; j++) a4[i][j] += a0[i]*b0[j];
    }
    __syncthreads();
    // diag bwd product
    LOAD_TILE(rs, rb + hb, 64);
    LOAD_TILE(ks, kb + hb, 64);
    __syncthreads();
    float b4[4][4] = {};
    #pragma unroll
    for (int kk = 0; kk < 64; kk++){
        float a0[4], b0[4];
        #pragma unroll
        for (int i = 0; i < 4; i++){ a0[i] = rs[ty+i][kk]; b0[i] = ks[tx+i][kk]; }
        #pragma unroll
        for (int i = 0; i < 4; i++)
            #pragma unroll
            for (int j = 0; j < 4; j++) b4[i][j] += a0[i]*b0[j];
    }
    #pragma unroll
    for (int i = 0; i < 4; i++)
        #pragma unroll
        for (int j = 0; j < 4; j++)
            at[ty+i][tx+j] = ((ty+i) >= (tx+j)) ? a4[i][j] : b4[i][j];
    __syncthreads();
    // y = at @ Pv_c
    LOAD_TILE(rs, X + hb, 64);
    __syncthreads();
    float yacc[4][4] = {};
    #pragma unroll 8
    for (int s = 0; s < 64; s++){
        float a0[4], b0[4];
        #pragma unroll
        for (int i = 0; i < 4; i++){ a0[i] = at[ty+i][s]; b0[i] = rs[s][tx+i]; }
        #pragma unroll
        for (int i = 0; i < 4; i++)
            #pragma unroll
            for (int j = 0; j < 4; j++) yacc[i][j] += a0[i]*b0[j];
    }
    __syncthreads();
    // y += rf_c @ Sf[c]
    LOAD_TILE(rs, Sf + sb, 64);
    LOAD_TILE(ks, rf + hb, 64);
    __syncthreads();
    #pragma unroll 8
    for (int kk = 0; kk < 64; kk++){
        float a0[4], b0[4];
        #pragma unroll
        for (int i = 0; i < 4; i++){ a0[i] = ks[ty+i][kk]; b0[i] = rs[kk][tx+i]; }
        #pragma unroll
        for (int i = 0; i < 4; i++)
            #pragma unroll
            for (int j = 0; j < 4; j++) yacc[i][j] += a0[i]*b0[j];
    }
    __syncthreads();
    // y += rb_c @ Sb[c]
    LOAD_TILE(rs, Sb + sb, 64);
    LOAD_TILE(ks, rb + hb, 64);
    __syncthreads();
    #pragma unroll 8
    for (int kk = 0; kk < 64; kk++){
        float a0[4], b0[4];
        #pragma unroll
        for (int i = 0; i < 4; i++){ a0[i] = ks[ty+i][kk]; b0[i] = rs[kk][tx+i]; }
        #pragma unroll
        for (int i = 0; i < 4; i++)
            #pragma unroll
            for (int j = 0; j < 4; j++) yacc[i][j] += a0[i]*b0[j];
    }
    #pragma unroll
    for (int i = 0; i < 4; i++)
        *(float4*)(y + hb + (size_t)(ty+i)*64 + tx) =
            make_float4(yacc[i][0], yacc[i][1], yacc[i][2], yacc[i][3]);
}

// ---------------- GroupNorm + gate ----------------
__global__ void k_gn(const float* __restrict__ y, const float* __restrict__ g,
                     const float* __restrict__ lnw, const float* __restrict__ lnb,
                     float* __restrict__ z){
    int gw = (blockIdx.x*256 + threadIdx.x) >> 6;
    int lane = threadIdx.x & 63;
    if (gw >= CB*CT*CH) return;
    int h = gw % CH; int bt = gw / CH;
    int b = bt / CT, t = bt % CT;
    int bh = b*CH + h;
    float yv = y[((size_t)bh*CT + t)*64 + lane];
    float s1 = yv, s2 = yv*yv;
    #pragma unroll
    for (int off = 32; off; off >>= 1){ s1 += __shfl_xor(s1, off); s2 += __shfl_xor(s2, off); }
    float mu = s1 * (1.f/64.f);
    float var = s2 * (1.f/64.f) - mu*mu;
    float inv = rsqrtf(var + 6.4e-4f);
    int d = h*64 + lane;
    float yn = (yv - mu)*inv*lnw[d] + lnb[d];
    z[(size_t)bt*CD + d] = yn * g[(size_t)bt*CD + d];
}

extern "C" void kernel_launch(void* const* d_in, const int* in_sizes, int n_in,
                              void* d_out, int out_size, void* d_ws, size_t ws_size,
                              hipStream_t stream){
    const float* x          = (const float*)d_in[0];
    const float* tmx        = (const float*)d_in[1];
    const float* tmw        = (const float*)d_in[2];
    const float* tmk        = (const float*)d_in[3];
    const float* tmv        = (const float*)d_in[4];
    const float* tmr        = (const float*)d_in[5];
    const float* tmg        = (const float*)d_in[6];
    const float* maa_w1     = (const float*)d_in[7];
    const float* maa_w2     = (const float*)d_in[8];
    const float* time_decay = (const float*)d_in[9];
    const float* decay_w1   = (const float*)d_in[10];
    const float* decay_w2   = (const float*)d_in[11];
    const float* lucid_temp = (const float*)d_in[12];
    const float* Wr         = (const float*)d_in[13];
    const float* Wk         = (const float*)d_in[14];
    const float* Wv         = (const float*)d_in[15];
    const float* Wg         = (const float*)d_in[16];
    const float* Wo         = (const float*)d_in[17];
    const float* lnw        = (const float*)d_in[18];
    const float* lnb        = (const float*)d_in[19];
    float* out = (float*)d_out;
    float* ws  = (float*)d_ws;

    const size_t S = (size_t)CB*CT*CD;
    float* b0 = ws;          // dxprev -> wbuf -> Yb -> Sb
    float* b1 = ws + 1*S;    // xxx -> xw -> rf
    float* b2 = ws + 2*S;    // xk -> kf
    float* b3 = ws + 3*S;    // xv -> rb
    float* b4 = ws + 4*S;    // xr -> kn -> Sf
    float* b5 = ws + 5*S;    // xg -> X (v -> Pv)
    float* b6 = ws + 6*S;    // rbuf -> y
    float* b7 = ws + 7*S;    // kbuf -> z
    float* b8 = ws + 8*S;    // vbuf -> kb
    float* b9 = ws + 9*S;    // gbuf
    float* mbuf = ws + 10*S;
    const size_t MB_F = 4096*160;
    size_t base_f = 10*S + MB_F;

    const size_t per_bh = (size_t)CT*CT + 16*NB*NB;
    size_t avail = ws_size / sizeof(float);
    int G = 1;
    if (avail > base_f + per_bh){
        size_t g = (avail - base_f) / per_bh;
        G = (g >= CBH) ? CBH : (int)g;
        if (G < 1) G = 1;
    }
    float* P    = ws + base_f;
    float* invL = P + (size_t)G*CT*CT;

    float* dxprev = b0; float* xxx = b1;
    float* xw = b1; float* xk = b2; float* xv = b3; float* xr = b4; float* xg = b5;
    float* rbuf = b6; float* kbuf = b7; float* vbuf = b8; float* gbuf = b9; float* wbuf = b0;
    float* kn = b4; float* X = b5;
    float* rf = b1; float* kf = b2; float* rb = b3; float* kb = b8;
    float* Yb = b0;
    float* Sf = b4; float* Sb = b0;   // kn dead after gram; Yb dead after solves
    float* ybuf = b6; float* zbuf = b7;

    k_shift<<<dim3((CB*CT*CD + 255)/256), 256, 0, stream>>>(x, tmx, dxprev, xxx);
    k_gemm<1><<<dim3(3, 32), 256, 0, stream>>>(xxx, maa_w1, nullptr, mbuf, 4096, 160, 768);
    k_mix5<<<dim3(3, 4096), 256, 0, stream>>>(x, dxprev, mbuf, tmw, tmk, tmv, tmr, tmg,
                                              maa_w2, xw, xk, xv, xr, xg);
    k_gemm<0><<<dim3(12, 32), 256, 0, stream>>>(xr, Wr, nullptr, rbuf, 4096, 768, 768);
    k_gemm<0><<<dim3(12, 32), 256, 0, stream>>>(xk, Wk, nullptr, kbuf, 4096, 768, 768);
    k_gemm<0><<<dim3(12, 32), 256, 0, stream>>>(xv, Wv, nullptr, vbuf, 4096, 768, 768);
    k_gemm<2><<<dim3(12, 32), 256, 0, stream>>>(xg, Wg, nullptr, gbuf, 4096, 768, 768);
    k_gemm<1><<<dim3(1, 32), 256, 0, stream>>>(xw, decay_w1, nullptr, mbuf, 4096, 64, 768);
    k_gemm<3><<<dim3(12, 32), 256, 0, stream>>>(mbuf, decay_w2, time_decay, wbuf, 4096, 768, 64);

    k_knvx<<<dim3((CB*CH*CT*64)/256), 256, 0, stream>>>(kbuf, vbuf, kn, X);
    k_scan2<<<dim3(CBH), 256, 0, stream>>>(rbuf, kbuf, wbuf, rf, kf, rb, kb);

    for (int bh0 = 0; bh0 < CBH; bh0 += G){
        int Gc = (CBH - bh0 < G) ? (CBH - bh0) : G;
        k_gram<<<dim3(16, 16, Gc), 256, 0, stream>>>(kn, lucid_temp, P, bh0);
        k_potrf0<<<dim3(Gc), 256, 0, stream>>>(P, invL);
        for (int jb = 0; jb < 15; jb++){
            int nt = 15 - jb;
            k_trsm<<<dim3(nt, Gc), 256, 0, stream>>>(P, invL, jb);
            k_syrkpo<<<dim3(nt, nt, Gc), 256, 0, stream>>>(P, invL, jb);
        }
        for (int jb = 0; jb < 16; jb++)
            k_solve<0><<<dim3(16-jb, Gc), 256, 0, stream>>>(P, invL, X, Yb, bh0, jb);
        for (int jb = 15; jb >= 0; jb--)
            k_solve<1><<<dim3(jb+1, Gc), 256, 0, stream>>>(P, invL, X, Yb, bh0, jb);
    }

    k_outer<<<dim3(16, CBH), 256, 0, stream>>>(kf, kb, X, Sf, Sb);
    k_cumsum<<<dim3(CBH), 256, 0, stream>>>(Sf, Sb);
    k_apv2<<<dim3(16, CBH), 256, 0, stream>>>(rf, kf, rb, kb, X, Sf, Sb, ybuf);
    k_gn<<<dim3((CB*CT*CH*64)/256), 256, 0, stream>>>(ybuf, gbuf, lnw, lnb, zbuf);
    k_gemm<0><<<dim3(12, 32), 256, 0, stream>>>(zbuf, Wo, nullptr, out, 4096, 768, 768);
}

// Round 6
// 5265.055 us; speedup vs baseline: 5.9146x; 1.1263x over previous
//
#include <hip/hip_runtime.h>
#include <math.h>

#define CB 4
#define CT 1024
#define CD 768
#define CH 12
#define CK 64
#define CBH (CB*CH)
#define NB 64

typedef __attribute__((ext_vector_type(8))) short sh8;
typedef __attribute__((ext_vector_type(8))) unsigned short ush8;
typedef __attribute__((ext_vector_type(4))) unsigned short ush4;
typedef __attribute__((ext_vector_type(4))) float fl4;

__device__ __forceinline__ unsigned short f2bf(float f){
    unsigned u = __builtin_bit_cast(unsigned, f);
    unsigned r = (u + 0x7fff + ((u >> 16) & 1)) >> 16;
    return (unsigned short)r;
}
__device__ __forceinline__ float bf2f(unsigned short u){
    return __builtin_bit_cast(float, (unsigned)u << 16);
}

// cooperative 64x64 tile load: global (row-major, given stride) -> LDS [64][65]
#define LOAD_TILE(dst, src, stride) { \
    _Pragma("unroll") \
    for (int i_ = 0; i_ < 4; i_++){ \
        int rr_ = (tid>>4) + i_*16, cc_ = (tid&15)*4; \
        float4 v_ = *(const float4*)((src) + (size_t)rr_*(stride) + cc_); \
        dst[rr_][cc_+0]=v_.x; dst[rr_][cc_+1]=v_.y; dst[rr_][cc_+2]=v_.z; dst[rr_][cc_+3]=v_.w; \
    } }

// ---------------- elementwise: token shift + xxx ----------------
__global__ void k_shift(const float* __restrict__ x, const float* __restrict__ tmx,
                        float* __restrict__ dxprev, float* __restrict__ xxx){
    int idx = blockIdx.x*256 + threadIdx.x;
    if (idx >= CB*CT*CD) return;
    int d = idx % CD;
    int bt = idx / CD;
    int t = bt % CT;
    float xc = x[idx];
    float xl = (t > 0)      ? x[idx - CD] : 0.f;
    float xr = (t < CT-1)   ? x[idx + CD] : 0.f;
    float dx = 0.5f*(xl + xr) - xc;
    dxprev[idx] = dx;
    xxx[idx] = xc + dx * tmx[d];
}

// ---------------- generic tiled fp32 GEMM (small shapes only now) ----------------
template<int MODE>
__global__ void k_gemm(const float* __restrict__ A, const float* __restrict__ Bm,
                       const float* __restrict__ bias, float* __restrict__ C,
                       int M, int N, int Kd){
    __shared__ float As[16][128];
    __shared__ float Bs[16][64];
    int tid = threadIdx.x;
    int m0 = blockIdx.y * 128, n0 = blockIdx.x * 64;
    int tn = (tid & 15) * 4;
    int tm = (tid >> 4) * 8;
    float acc[8][4] = {};
    for (int k0 = 0; k0 < Kd; k0 += 16){
        #pragma unroll
        for (int i = 0; i < 8; i++){
            int e = tid + i*256;
            int r = e >> 4, c = e & 15;
            As[c][r] = A[(size_t)(m0+r)*Kd + k0 + c];
        }
        #pragma unroll
        for (int i = 0; i < 4; i++){
            int e = tid + i*256;
            int r = e >> 6, c = e & 63;
            float bv = 0.f;
            if (n0 + c < N) bv = Bm[(size_t)(k0+r)*N + n0 + c];
            Bs[r][c] = bv;
        }
        __syncthreads();
        #pragma unroll
        for (int kk = 0; kk < 16; kk++){
            float a0[8], b0[4];
            #pragma unroll
            for (int i = 0; i < 8; i++) a0[i] = As[kk][tm+i];
            #pragma unroll
            for (int j = 0; j < 4; j++) b0[j] = Bs[kk][tn+j];
            #pragma unroll
            for (int i = 0; i < 8; i++)
                #pragma unroll
                for (int j = 0; j < 4; j++) acc[i][j] += a0[i]*b0[j];
        }
        __syncthreads();
    }
    #pragma unroll
    for (int i = 0; i < 8; i++)
        #pragma unroll
        for (int j = 0; j < 4; j++){
            int mm = m0 + tm + i, nn = n0 + tn + j;
            if (nn < N){
                float v = acc[i][j];
                if (MODE == 1) v = tanhf(v);
                else if (MODE == 2) v = v / (1.f + expf(-v));
                else if (MODE == 3) v += bias[nn];
                C[(size_t)mm*N + nn] = v;
            }
        }
}

// ---------------- weight transpose + split to bf16 hi/lo: B[K][N] -> Bt{Hi,Lo}[N][K] ----------------
__global__ void k_splitT(const float* __restrict__ B, unsigned short* __restrict__ hi,
                         unsigned short* __restrict__ lo, int Kd, int N){
    __shared__ float ts[64][65];
    int tid = threadIdx.x;
    int n0 = blockIdx.x*64, k0 = blockIdx.y*64;
    #pragma unroll
    for (int i = 0; i < 4; i++){
        int rr = (tid>>4) + i*16, cc = (tid&15)*4;
        float4 v = *(const float4*)(B + (size_t)(k0+rr)*N + n0 + cc);
        ts[rr][cc+0]=v.x; ts[rr][cc+1]=v.y; ts[rr][cc+2]=v.z; ts[rr][cc+3]=v.w;
    }
    __syncthreads();
    #pragma unroll
    for (int i = 0; i < 4; i++){
        int nl = (tid>>4) + i*16, k4 = (tid&15)*4;
        ush4 vh, vl;
        #pragma unroll
        for (int j = 0; j < 4; j++){
            float f = ts[k4+j][nl];
            unsigned short h = f2bf(f);
            vh[j] = h;
            vl[j] = f2bf(f - bf2f(h));
        }
        size_t o = (size_t)(n0+nl)*Kd + k0 + k4;
        *reinterpret_cast<ush4*>(hi + o) = vh;
        *reinterpret_cast<ush4*>(lo + o) = vl;
    }
}

// ---------------- MFMA split-bf16 GEMM: C[M,N] = A[M,K] @ Bt[N,K]^T ----------------
// BM=BN=64, BK=32, 256 threads = 4 waves (2x2), each wave 32x32 out (2x2 frags of 16x16)
template<int MODE>
__global__ __launch_bounds__(256) void k_mgemm(const float* __restrict__ A,
        const unsigned short* __restrict__ BtHi, const unsigned short* __restrict__ BtLo,
        float* __restrict__ C, int M, int N, int Kd){
    __shared__ unsigned short AHI[2048], ALO[2048], BHI[2048], BLO[2048];
    int tid = threadIdx.x;
    int n0 = blockIdx.x*64, m0 = blockIdx.y*64;
    int w = tid >> 6, lane = tid & 63;
    int wm = w >> 1, wn = w & 1;
    fl4 acc[2][2];
    #pragma unroll
    for (int mi = 0; mi < 2; mi++)
        #pragma unroll
        for (int ni = 0; ni < 2; ni++) acc[mi][ni] = (fl4){0.f, 0.f, 0.f, 0.f};
    int sm = tid >> 2;                        // slot row 0..63
    int sk = (tid & 3) * 8;                   // k offset within BK
    int slane = (sm & 15) + ((tid & 3) << 4); // frag lane
    int sidx = (((sm >> 4)*64) + slane) * 8;  // ushort index in LDS
    const int nsteps = Kd >> 5;
    for (int ks = 0; ks < nsteps; ks++){
        int k0 = ks << 5;
        __syncthreads();
        {   // stage A (fp32 -> split bf16, frag-major)
            const float* ap = A + (size_t)(m0+sm)*Kd + k0 + sk;
            float4 a0 = *(const float4*)ap, a1 = *(const float4*)(ap+4);
            float av[8] = {a0.x,a0.y,a0.z,a0.w,a1.x,a1.y,a1.z,a1.w};
            ush8 vh, vl;
            #pragma unroll
            for (int i = 0; i < 8; i++){
                unsigned short h = f2bf(av[i]);
                vh[i] = h;
                vl[i] = f2bf(av[i] - bf2f(h));
            }
            *reinterpret_cast<ush8*>(&AHI[sidx]) = vh;
            *reinterpret_cast<ush8*>(&ALO[sidx]) = vl;
            // stage B (pre-split bf16, frag-major)
            size_t bo = (size_t)(n0+sm)*Kd + k0 + sk;
            *reinterpret_cast<ush8*>(&BHI[sidx]) = *reinterpret_cast<const ush8*>(BtHi + bo);
            *reinterpret_cast<ush8*>(&BLO[sidx]) = *reinterpret_cast<const ush8*>(BtLo + bo);
        }
        __syncthreads();
        sh8 ah[2], al[2], bh[2], bl[2];
        #pragma unroll
        for (int mi = 0; mi < 2; mi++){
            int gm = wm*2 + mi;
            ah[mi] = *reinterpret_cast<sh8*>(&AHI[(gm*64 + lane)*8]);
            al[mi] = *reinterpret_cast<sh8*>(&ALO[(gm*64 + lane)*8]);
        }
        #pragma unroll
        for (int ni = 0; ni < 2; ni++){
            int gn = wn*2 + ni;
            bh[ni] = *reinterpret_cast<sh8*>(&BHI[(gn*64 + lane)*8]);
            bl[ni] = *reinterpret_cast<sh8*>(&BLO[(gn*64 + lane)*8]);
        }
        #pragma unroll
        for (int mi = 0; mi < 2; mi++)
            #pragma unroll
            for (int ni = 0; ni < 2; ni++){
                acc[mi][ni] = __builtin_amdgcn_mfma_f32_16x16x32_bf16(al[mi], bh[ni], acc[mi][ni], 0, 0, 0);
                acc[mi][ni] = __builtin_amdgcn_mfma_f32_16x16x32_bf16(ah[mi], bl[ni], acc[mi][ni], 0, 0, 0);
                acc[mi][ni] = __builtin_amdgcn_mfma_f32_16x16x32_bf16(ah[mi], bh[ni], acc[mi][ni], 0, 0, 0);
            }
    }
    // epilogue: D[(lane>>4)*4+j][lane&15] per frag
    #pragma unroll
    for (int mi = 0; mi < 2; mi++)
        #pragma unroll
        for (int ni = 0; ni < 2; ni++){
            int cc = n0 + wn*32 + ni*16 + (lane & 15);
            int rb = m0 + wm*32 + mi*16 + ((lane >> 4) << 2);
            #pragma unroll
            for (int j = 0; j < 4; j++){
                float v = acc[mi][ni][j];
                if (MODE == 2) v = v / (1.f + expf(-v));
                C[(size_t)(rb+j)*N + cc] = v;
            }
        }
}

// ---------------- 5-way low-rank mix ----------------
__global__ void k_mix5(const float* __restrict__ x, const float* __restrict__ dxprev,
                       const float* __restrict__ m,
                       const float* __restrict__ tmw, const float* __restrict__ tmk,
                       const float* __restrict__ tmv, const float* __restrict__ tmr,
                       const float* __restrict__ tmg, const float* __restrict__ w2,
                       float* __restrict__ xw, float* __restrict__ xk, float* __restrict__ xv,
                       float* __restrict__ xr, float* __restrict__ xg){
    __shared__ float ms[160];
    int i = blockIdx.y;
    int j = blockIdx.x*256 + threadIdx.x;
    if (threadIdx.x < 160) ms[threadIdx.x] = m[(size_t)i*160 + threadIdx.x];
    __syncthreads();
    float xc = x[(size_t)i*CD + j], dx = dxprev[(size_t)i*CD + j];
    const float* tms[5] = {tmw, tmk, tmv, tmr, tmg};
    float* outs[5] = {xw, xk, xv, xr, xg};
    #pragma unroll
    for (int c = 0; c < 5; c++){
        float s = tms[c][j];
        const float* w2c = w2 + (size_t)c*32*CD + j;
        #pragma unroll
        for (int dm = 0; dm < 32; dm++) s += ms[c*32+dm] * w2c[(size_t)dm*CD];
        outs[c][(size_t)i*CD + j] = xc + dx*s;
    }
}

// ---------------- normalize k, stage v into X (head layout) ----------------
__global__ void k_knvx(const float* __restrict__ k, const float* __restrict__ v,
                       float* __restrict__ kn, float* __restrict__ X){
    int gw = (blockIdx.x*256 + threadIdx.x) >> 6;
    int lane = threadIdx.x & 63;
    if (gw >= CB*CH*CT) return;
    int t = gw % CT; int bh = gw / CT; int h = bh % CH; int b = bh / CH;
    size_t src = ((size_t)(b*CT + t))*CD + h*64 + lane;
    float kv = k[src];
    float ss = kv*kv;
    #pragma unroll
    for (int off = 32; off; off >>= 1) ss += __shfl_xor(ss, off);
    float nrm = fmaxf(sqrtf(ss), 1e-12f);
    size_t dst = ((size_t)bh*CT + t)*64 + lane;
    kn[dst] = kv / nrm;
    X[dst]  = v[src];
}

// ---------------- decay scan, fully coalesced ----------------
__global__ __launch_bounds__(256) void k_scan2(const float* __restrict__ r, const float* __restrict__ k,
                        const float* __restrict__ w,
                        float* __restrict__ rf, float* __restrict__ kf,
                        float* __restrict__ rb, float* __restrict__ kb){
    __shared__ float parts[16][4][64];
    __shared__ float carr[16][64];
    __shared__ float refs[2][64];
    int bh = blockIdx.x; int h = bh % CH; int b = bh / CH;
    int tid = threadIdx.x; int wid = tid >> 6; int ch = tid & 63;
    const float* wb = w + (size_t)b*CT*CD + h*64;
    for (int tc = 0; tc < 16; tc++){
        float sum = 0.f;
        int tb = tc*64 + wid*16;
        for (int s = 0; s < 16; s++)
            sum -= expf(wb[(size_t)(tb+s)*CD + ch]);
        parts[tc][wid][ch] = sum;
    }
    __syncthreads();
    if (tid < 64){
        float run = 0.f;
        for (int tc = 0; tc < 16; tc++){
            carr[tc][tid] = run;
            run += parts[tc][0][tid] + parts[tc][1][tid] + parts[tc][2][tid] + parts[tc][3][tid];
        }
        float wv512 = -expf(wb[(size_t)512*CD + tid]);
        refs[0][tid] = carr[8][tid] + wv512;
        refs[1][tid] = carr[8][tid];
    }
    __syncthreads();
    const float* rbp = r + (size_t)b*CT*CD + h*64;
    const float* kbp = k + (size_t)b*CT*CD + h*64;
    size_t ob = (size_t)bh*CT*64;
    float ref_f = refs[0][ch], ref_b = refs[1][ch];
    for (int tc = 0; tc < 16; tc++){
        float run = carr[tc][ch];
        if (wid > 0) run += parts[tc][0][ch];
        if (wid > 1) run += parts[tc][1][ch];
        if (wid > 2) run += parts[tc][2][ch];
        int tb = tc*64 + wid*16;
        for (int s = 0; s < 16; s++){
            int t = tb + s;
            float wv = -expf(wb[(size_t)t*CD + ch]);
            run += wv;
            float csf = fminf(fmaxf(run - ref_f, -60.f), 60.f);
            float csb = fminf(fmaxf((run - wv) - ref_b, -60.f), 60.f);
            float rv = rbp[(size_t)t*CD + ch], kv = kbp[(size_t)t*CD + ch];
            rf[ob + (size_t)t*64 + ch] = rv * expf(csf);
            kf[ob + (size_t)t*64 + ch] = kv * expf(-csf);
            rb[ob + (size_t)t*64 + ch] = rv * expf(-csb);
            kb[ob + (size_t)t*64 + ch] = kv * expf(csb);
        }
    }
}

// ---------------- P(lower) = I + exp(clip(temp * kn knT)) ----------------
__global__ void k_gram(const float* __restrict__ kn, const float* __restrict__ lucid_temp,
                       float* __restrict__ P, int bh0){
    int t0 = blockIdx.y*64, s0 = blockIdx.x*64;
    if (t0 < s0) return;
    __shared__ float tA[64][65];
    __shared__ float tB[64][65];
    int lbh = blockIdx.z; int gbh = bh0 + lbh; int h = gbh % CH;
    int tid = threadIdx.x;
    LOAD_TILE(tA, kn + ((size_t)gbh*CT + t0)*64, 64);
    LOAD_TILE(tB, kn + ((size_t)gbh*CT + s0)*64, 64);
    __syncthreads();
    float tv = lucid_temp[h];
    tv = (tv > 20.f) ? tv : log1pf(expf(tv));
    int ty = (tid >> 4)*4, tx = (tid & 15)*4;
    float acc[4][4] = {};
    #pragma unroll
    for (int kk = 0; kk < 64; kk++){
        float a0[4], b0[4];
        #pragma unroll
        for (int i = 0; i < 4; i++){ a0[i] = tA[ty+i][kk]; b0[i] = tB[tx+i][kk]; }
        #pragma unroll
        for (int i = 0; i < 4; i++)
            #pragma unroll
            for (int j = 0; j < 4; j++) acc[i][j] += a0[i]*b0[j];
    }
    size_t pbase = (size_t)lbh*CT*CT;
    #pragma unroll
    for (int i = 0; i < 4; i++){
        int tt = t0+ty+i;
        float4 v;
        float g0 = fminf(fmaxf(tv*acc[i][0], -20.f), 20.f);
        float g1 = fminf(fmaxf(tv*acc[i][1], -20.f), 20.f);
        float g2 = fminf(fmaxf(tv*acc[i][2], -20.f), 20.f);
        float g3 = fminf(fmaxf(tv*acc[i][3], -20.f), 20.f);
        v.x = expf(g0) + ((tt == s0+tx+0) ? 1.f : 0.f);
        v.y = expf(g1) + ((tt == s0+tx+1) ? 1.f : 0.f);
        v.z = expf(g2) + ((tt == s0+tx+2) ? 1.f : 0.f);
        v.w = expf(g3) + ((tt == s0+tx+3) ? 1.f : 0.f);
        *(float4*)(P + pbase + (size_t)tt*CT + s0 + tx) = v;
    }
}

// ---------------- in-LDS 64x64 Cholesky + triangular inverse ----------------
__device__ __forceinline__ void potrf_inv(float (&s)[64][65], float (&inv)[64][65], int tid){
    for (int j = 0; j < 63; j++){
        __syncthreads();
        float invd = 1.f / fmaxf(s[j][j], 1e-20f);
        int n = 63 - j;
        for (int e = tid; e < n*n; e += 256){
            int ii = j+1 + e / n, cc = j+1 + e % n;
            s[ii][cc] -= s[ii][j]*s[cc][j]*invd;
        }
    }
    __syncthreads();
    for (int e = tid; e < 64*64; e += 256){
        int i2 = e >> 6, j2 = e & 63;
        if (i2 > j2) s[i2][j2] *= rsqrtf(fmaxf(s[j2][j2], 1e-20f));
    }
    __syncthreads();
    if (tid < 64) s[tid][tid] = sqrtf(fmaxf(s[tid][tid], 1e-20f));
    __syncthreads();
    if (tid < 64){
        int c = tid;
        for (int j = 0; j < c; j++) inv[j][c] = 0.f;
        for (int j = c; j < 64; j++){
            float sum = (j == c) ? 1.f : 0.f;
            for (int kk = c; kk < j; kk++) sum -= s[j][kk]*inv[kk][c];
            inv[j][c] = sum / s[j][j];
        }
    }
    __syncthreads();
}

__device__ __forceinline__ void potrf_writeout(float (&s)[64][65], float (&inv)[64][65], int tid,
                                               float* __restrict__ Pd, float* __restrict__ invp){
    for (int e = tid; e < 4096; e += 256){
        int r2 = e >> 6, c2 = e & 63;
        if (c2 <= r2) Pd[(size_t)r2*CT + c2] = s[r2][c2];
    }
    #pragma unroll
    for (int i_ = 0; i_ < 4; i_++){
        int rr_ = (tid>>4) + i_*16, cc_ = (tid&15)*4;
        float4 v_ = make_float4(inv[rr_][cc_], inv[rr_][cc_+1], inv[rr_][cc_+2], inv[rr_][cc_+3]);
        *(float4*)(invp + rr_*64 + cc_) = v_;
    }
}

__global__ void k_potrf0(float* __restrict__ P, float* __restrict__ invL){
    __shared__ float s[64][65], inv[64][65];
    int bh = blockIdx.x; int tid = threadIdx.x;
    size_t base = (size_t)bh*CT*CT;
    LOAD_TILE(s, P + base, CT);
    __syncthreads();
    potrf_inv(s, inv, tid);
    potrf_writeout(s, inv, tid, P + base, invL + (size_t)bh*16*4096);
}

// ---------------- TRSM: panel = A21 @ invL11^T ----------------
__global__ void k_trsm(float* __restrict__ P, const float* __restrict__ invL, int jb){
    __shared__ float a[64][65];
    __shared__ float iv[64][65];
    int bh = blockIdx.y;
    int r0 = (jb+1)*NB + blockIdx.x*64;
    int j0 = jb*NB;
    size_t base = (size_t)bh*CT*CT;
    int tid = threadIdx.x;
    const float* invp = invL + ((size_t)bh*16 + jb)*4096;
    LOAD_TILE(a, P + base + (size_t)r0*CT + j0, CT);
    LOAD_TILE(iv, invp, 64);
    __syncthreads();
    int ty = (tid >> 4)*4, tx = (tid & 15)*4;
    float acc[4][4] = {};
    #pragma unroll
    for (int kk = 0; kk < 64; kk++){
        float a0[4], b0[4];
        #pragma unroll
        for (int i = 0; i < 4; i++){ a0[i] = a[ty+i][kk]; b0[i] = iv[tx+i][kk]; }
        #pragma unroll
        for (int i = 0; i < 4; i++)
            #pragma unroll
            for (int j = 0; j < 4; j++) acc[i][j] += a0[i]*b0[j];
    }
    #pragma unroll
    for (int i = 0; i < 4; i++)
        *(float4*)(P + base + (size_t)(r0+ty+i)*CT + j0 + tx) =
            make_float4(acc[i][0], acc[i][1], acc[i][2], acc[i][3]);
}

// ---------------- SYRK (lower tiles) + inline potrf of next diagonal ----------------
__global__ void k_syrkpo(float* __restrict__ P, float* __restrict__ invL, int jb){
    int ti = blockIdx.y, tj = blockIdx.x;
    if (tj > ti) return;
    int bh = blockIdx.z;
    int off = (jb+1)*NB;
    int r0 = off + ti*64, c0 = off + tj*64;
    int j0 = jb*NB;
    size_t base = (size_t)bh*CT*CT;
    __shared__ float La[64][65], Lb[64][65];
    int tid = threadIdx.x;
    LOAD_TILE(La, P + base + (size_t)r0*CT + j0, CT);
    LOAD_TILE(Lb, P + base + (size_t)c0*CT + j0, CT);
    __syncthreads();
    int ty = (tid >> 4)*4, tx = (tid & 15)*4;
    float acc[4][4] = {};
    #pragma unroll
    for (int kk = 0; kk < 64; kk++){
        float a0[4], b0[4];
        #pragma unroll
        for (int i = 0; i < 4; i++){ a0[i] = La[ty+i][kk]; b0[i] = Lb[tx+i][kk]; }
        #pragma unroll
        for (int i = 0; i < 4; i++)
            #pragma unroll
            for (int j = 0; j < 4; j++) acc[i][j] += a0[i]*b0[j];
    }
    if (!(ti == 0 && tj == 0)){
        #pragma unroll
        for (int i = 0; i < 4; i++){
            float4* p4 = (float4*)(P + base + (size_t)(r0+ty+i)*CT + c0 + tx);
            float4 v = *p4;
            v.x -= acc[i][0]; v.y -= acc[i][1]; v.z -= acc[i][2]; v.w -= acc[i][3];
            *p4 = v;
        }
    } else {
        __syncthreads();
        #pragma unroll
        for (int i = 0; i < 4; i++){
            float4 v = *(const float4*)(P + base + (size_t)(r0+ty+i)*CT + c0 + tx);
            La[ty+i][tx+0] = v.x - acc[i][0];
            La[ty+i][tx+1] = v.y - acc[i][1];
            La[ty+i][tx+2] = v.z - acc[i][2];
            La[ty+i][tx+3] = v.w - acc[i][3];
        }
        __syncthreads();
        potrf_inv(La, Lb, tid);
        potrf_writeout(La, Lb, tid, P + base + (size_t)off*CT + off,
                       invL + ((size_t)bh*16 + jb+1)*4096);
    }
}

// ---------------- fused block substitution ----------------
template<int TRANS>
__global__ void k_solve(const float* __restrict__ P, const float* __restrict__ invL,
                        float* __restrict__ Xc, float* __restrict__ Yb, int bh0, int jb){
    __shared__ float A[64][65], B[64][65], C[64][65];
    int bh = blockIdx.y, tid = threadIdx.x;
    int ib = TRANS ? blockIdx.x : (jb + blockIdx.x);
    const float* invp = invL + ((size_t)bh*16 + jb)*4096;
    const float* src = (TRANS ? Yb : Xc) + ((size_t)(bh0+bh)*CT + jb*64)*64;
    LOAD_TILE(A, invp, 64);
    LOAD_TILE(B, src, 64);
    __syncthreads();
    int ty = (tid >> 4)*4, tx = (tid & 15)*4;
    float c4[4][4] = {};
    #pragma unroll
    for (int kk = 0; kk < 64; kk++){
        float a0[4], b0[4];
        #pragma unroll
        for (int i = 0; i < 4; i++){
            a0[i] = TRANS ? A[kk][ty+i] : A[ty+i][kk];
            b0[i] = B[kk][tx+i];
        }
        #pragma unroll
        for (int i = 0; i < 4; i++)
            #pragma unroll
            for (int j = 0; j < 4; j++) c4[i][j] += a0[i]*b0[j];
    }
    if (ib == jb){
        float* dst = (TRANS ? Xc : Yb) + ((size_t)(bh0+bh)*CT + jb*64)*64;
        #pragma unroll
        for (int i = 0; i < 4; i++)
            *(float4*)(dst + (size_t)(ty+i)*64 + tx) =
                make_float4(c4[i][0], c4[i][1], c4[i][2], c4[i][3]);
        return;
    }
    #pragma unroll
    for (int i = 0; i < 4; i++)
        #pragma unroll
        for (int j = 0; j < 4; j++) C[ty+i][tx+j] = c4[i][j];
    __syncthreads();
    const float* Lp = P + (size_t)bh*CT*CT + (TRANS ? ((size_t)(jb*64)*CT + ib*64)
                                                    : ((size_t)(ib*64)*CT + jb*64));
    LOAD_TILE(A, Lp, CT);
    __syncthreads();
    float u4[4][4] = {};
    #pragma unroll
    for (int kk = 0; kk < 64; kk++){
        float a0[4], b0[4];
        #pragma unroll
        for (int i = 0; i < 4; i++){
            a0[i] = TRANS ? A[kk][ty+i] : A[ty+i][kk];
            b0[i] = C[kk][tx+i];
        }
        #pragma unroll
        for (int i = 0; i < 4; i++)
            #pragma unroll
            for (int j = 0; j < 4; j++) u4[i][j] += a0[i]*b0[j];
    }
    float* dst = (TRANS ? Yb : Xc) + ((size_t)(bh0+bh)*CT + ib*64)*64;
    #pragma unroll
    for (int i = 0; i < 4; i++){
        float4* p4 = (float4*)(dst + (size_t)(ty+i)*64 + tx);
        float4 v = *p4;
        v.x -= u4[i][0]; v.y -= u4[i][1]; v.z -= u4[i][2]; v.w -= u4[i][3];
        *p4 = v;
    }
}

// ---------------- per-chunk outer products ----------------
__global__ void k_outer(const float* __restrict__ kf, const float* __restrict__ kb,
                        const float* __restrict__ X,
                        float* __restrict__ Sf, float* __restrict__ Sb){
    __shared__ float kfs[64][65], kbs[64][65], pvs[64][65];
    int c = blockIdx.x, bh = blockIdx.y, tid = threadIdx.x;
    size_t hb = (size_t)bh*CT*64 + (size_t)c*64*64;
    LOAD_TILE(kfs, kf + hb, 64);
    LOAD_TILE(kbs, kb + hb, 64);
    LOAD_TILE(pvs, X + hb, 64);
    __syncthreads();
    int ty = (tid >> 4)*4, tx = (tid & 15)*4;
    float af[4][4] = {}, ab[4][4] = {};
    #pragma unroll
    for (int kk = 0; kk < 64; kk++){
        float f0[4], g0[4], b0[4];
        #pragma unroll
        for (int i = 0; i < 4; i++){
            f0[i] = kfs[kk][ty+i];
            g0[i] = kbs[kk][ty+i];
            b0[i] = pvs[kk][tx+i];
        }
        #pragma unroll
        for (int i = 0; i < 4; i++)
            #pragma unroll
            for (int j = 0; j < 4; j++){
                af[i][j] += f0[i]*b0[j];
                ab[i][j] += g0[i]*b0[j];
            }
    }
    size_t sb = ((size_t)bh*16 + c)*4096;
    #pragma unroll
    for (int i = 0; i < 4; i++){
        *(float4*)(Sf + sb + (size_t)(ty+i)*64 + tx) = make_float4(af[i][0], af[i][1], af[i][2], af[i][3]);
        *(float4*)(Sb + sb + (size_t)(ty+i)*64 + tx) = make_float4(ab[i][0], ab[i][1], ab[i][2], ab[i][3]);
    }
}

// ---------------- in-place chunk-state cumsum ----------------
__global__ void k_cumsum(float* __restrict__ Sf, float* __restrict__ Sb){
    int bh = blockIdx.x, tid = threadIdx.x;
    size_t base = (size_t)bh*16*4096;
    #pragma unroll
    for (int i = 0; i < 16; i++){
        int e = tid + i*256;
        float run = 0.f;
        for (int c = 0; c < 16; c++){
            float* p = Sf + base + (size_t)c*4096 + e;
            float t = *p; *p = run; run += t;
        }
        run = 0.f;
        for (int c = 15; c >= 0; c--){
            float* p = Sb + base + (size_t)c*4096 + e;
            float t = *p; *p = run; run += t;
        }
    }
}

// ---------------- per-chunk y: masked diag + state GEMMs ----------------
__global__ void k_apv2(const float* __restrict__ rf, const float* __restrict__ kf,
                       const float* __restrict__ rb, const float* __restrict__ kb,
                       const float* __restrict__ X,
                       const float* __restrict__ Sf, const float* __restrict__ Sb,
                       float* __restrict__ y){
    __shared__ float rs[64][65], ks[64][65], at[64][65];
    int c = blockIdx.x, bh = blockIdx.y, tid = threadIdx.x;
    size_t hb = (size_t)bh*CT*64 + (size_t)c*64*64;
    size_t sb = ((size_t)bh*16 + c)*4096;
    int ty = (tid >> 4)*4, tx = (tid & 15)*4;
    LOAD_TILE(rs, rf + hb, 64);
    LOAD_TILE(ks, kf + hb, 64);
    __syncthreads();
    float a4[4][4] = {};
    #pragma unroll
    for (int kk = 0; kk < 64; kk++){
        float a0[4], b0[4];
        #pragma unroll
        for (int i = 0; i < 4; i++){ a0[i] = rs[ty+i][kk]; b0[i] = ks[tx+i][kk]; }
        #pragma unroll
        for (int i = 0; i < 4; i++)
            #pragma unroll
            for (int j = 0; j < 4; j++) a4[i][j] += a0[i]*b0[j];
    }
    __syncthreads();
    LOAD_TILE(rs, rb + hb, 64);
    LOAD_TILE(ks, kb + hb, 64);
    __syncthreads();
    float b4[4][4] = {};
    #pragma unroll
    for (int kk = 0; kk < 64; kk++){
        float a0[4], b0[4];
        #pragma unroll
        for (int i = 0; i < 4; i++){ a0[i] = rs[ty+i][kk]; b0[i] = ks[tx+i][kk]; }
        #pragma unroll
        for (int i = 0; i < 4; i++)
            #pragma unroll
            for (int j = 0; j < 4; j++) b4[i][j] += a0[i]*b0[j];
    }
    #pragma unroll
    for (int i = 0; i < 4; i++)
        #pragma unroll
        for (int j = 0; j < 4; j++)
            at[ty+i][tx+j] = ((ty+i) >= (tx+j)) ? a4[i][j] : b4[i][j];
    __syncthreads();
    LOAD_TILE(rs, X + hb, 64);
    __syncthreads();
    float yacc[4][4] = {};
    #pragma unroll 8
    for (int s = 0; s < 64; s++){
        float a0[4], b0[4];
        #pragma unroll
        for (int i = 0; i < 4; i++){ a0[i] = at[ty+i][s]; b0[i] = rs[s][tx+i]; }
        #pragma unroll
        for (int i = 0; i < 4; i++)
            #pragma unroll
            for (int j = 0; j < 4; j++) yacc[i][j] += a0[i]*b0[j];
    }
    __syncthreads();
    LOAD_TILE(rs, Sf + sb, 64);
    LOAD_TILE(ks, rf + hb, 64);
    __syncthreads();
    #pragma unroll 8
    for (int kk = 0; kk < 64; kk++){
        float a0[4], b0[4];
        #pragma unroll
        for (int i = 0; i < 4; i++){ a0[i] = ks[ty+i][kk]; b0[i] = rs[kk][tx+i]; }
        #pragma unroll
        for (int i = 0; i < 4; i++)
            #pragma unroll
            for (int j = 0; j < 4; j++) yacc[i][j] += a0[i]*b0[j];
    }
    __syncthreads();
    LOAD_TILE(rs, Sb + sb, 64);
    LOAD_TILE(ks, rb + hb, 64);
    __syncthreads();
    #pragma unroll 8
    for (int kk = 0; kk < 64; kk++){
        float a0[4], b0[4];
        #pragma unroll
        for (int i = 0; i < 4; i++){ a0[i] = ks[ty+i][kk]; b0[i] = rs[kk][tx+i]; }
        #pragma unroll
        for (int i = 0; i < 4; i++)
            #pragma unroll
            for (int j = 0; j < 4; j++) yacc[i][j] += a0[i]*b0[j];
    }
    #pragma unroll
    for (int i = 0; i < 4; i++)
        *(float4*)(y + hb + (size_t)(ty+i)*64 + tx) =
            make_float4(yacc[i][0], yacc[i][1], yacc[i][2], yacc[i][3]);
}

// ---------------- GroupNorm + gate ----------------
__global__ void k_gn(const float* __restrict__ y, const float* __restrict__ g,
                     const float* __restrict__ lnw, const float* __restrict__ lnb,
                     float* __restrict__ z){
    int gw = (blockIdx.x*256 + threadIdx.x) >> 6;
    int lane = threadIdx.x & 63;
    if (gw >= CB*CT*CH) return;
    int h = gw % CH; int bt = gw / CH;
    int b = bt / CT, t = bt % CT;
    int bh = b*CH + h;
    float yv = y[((size_t)bh*CT + t)*64 + lane];
    float s1 = yv, s2 = yv*yv;
    #pragma unroll
    for (int off = 32; off; off >>= 1){ s1 += __shfl_xor(s1, off); s2 += __shfl_xor(s2, off); }
    float mu = s1 * (1.f/64.f);
    float var = s2 * (1.f/64.f) - mu*mu;
    float inv = rsqrtf(var + 6.4e-4f);
    int d = h*64 + lane;
    float yn = (yv - mu)*inv*lnw[d] + lnb[d];
    z[(size_t)bt*CD + d] = yn * g[(size_t)bt*CD + d];
}

extern "C" void kernel_launch(void* const* d_in, const int* in_sizes, int n_in,
                              void* d_out, int out_size, void* d_ws, size_t ws_size,
                              hipStream_t stream){
    const float* x          = (const float*)d_in[0];
    const float* tmx        = (const float*)d_in[1];
    const float* tmw        = (const float*)d_in[2];
    const float* tmk        = (const float*)d_in[3];
    const float* tmv        = (const float*)d_in[4];
    const float* tmr        = (const float*)d_in[5];
    const float* tmg        = (const float*)d_in[6];
    const float* maa_w1     = (const float*)d_in[7];
    const float* maa_w2     = (const float*)d_in[8];
    const float* time_decay = (const float*)d_in[9];
    const float* decay_w1   = (const float*)d_in[10];
    const float* decay_w2   = (const float*)d_in[11];
    const float* lucid_temp = (const float*)d_in[12];
    const float* Wr         = (const float*)d_in[13];
    const float* Wk         = (const float*)d_in[14];
    const float* Wv         = (const float*)d_in[15];
    const float* Wg         = (const float*)d_in[16];
    const float* Wo         = (const float*)d_in[17];
    const float* lnw        = (const float*)d_in[18];
    const float* lnb        = (const float*)d_in[19];
    float* out = (float*)d_out;
    float* ws  = (float*)d_ws;

    const size_t S = (size_t)CB*CT*CD;
    float* b0 = ws;          // dxprev -> wbuf -> Yb -> Sb
    float* b1 = ws + 1*S;    // xxx -> xw -> rf
    float* b2 = ws + 2*S;    // xk -> kf
    float* b3 = ws + 3*S;    // xv -> rb
    float* b4 = ws + 4*S;    // xr -> kn -> Sf
    float* b5 = ws + 5*S;    // xg -> X (v -> Pv)
    float* b6 = ws + 6*S;    // rbuf -> y
    float* b7 = ws + 7*S;    // kbuf -> z
    float* b8 = ws + 8*S;    // vbuf -> kb
    float* b9 = ws + 9*S;    // gbuf
    float* mbuf = ws + 10*S;
    const size_t MB_F = 4096*160;
    size_t base_f = 10*S + MB_F;

    const size_t per_bh = (size_t)CT*CT + 16*NB*NB;
    size_t avail = ws_size / sizeof(float);
    int G = 1;
    if (avail > base_f + per_bh){
        size_t g = (avail - base_f) / per_bh;
        G = (g >= CBH) ? CBH : (int)g;
        if (G < 1) G = 1;
    }
    float* P    = ws + base_f;
    float* invL = P + (size_t)G*CT*CT;

    // weight split scratch lives in the P region (dead until k_gram; P >= 1M floats > 0.59M needed)
    unsigned short* BtHi = (unsigned short*)P;
    unsigned short* BtLo = BtHi + (size_t)CD*CD;

    float* dxprev = b0; float* xxx = b1;
    float* xw = b1; float* xk = b2; float* xv = b3; float* xr = b4; float* xg = b5;
    float* rbuf = b6; float* kbuf = b7; float* vbuf = b8; float* gbuf = b9; float* wbuf = b0;
    float* kn = b4; float* X = b5;
    float* rf = b1; float* kf = b2; float* rb = b3; float* kb = b8;
    float* Yb = b0;
    float* Sf = b4; float* Sb = b0;
    float* ybuf = b6; float* zbuf = b7;

    dim3 mg(CD/64, (CB*CT)/64);   // (12, 64)
    dim3 tg(CD/64, CD/64);        // (12, 12)

    k_shift<<<dim3((CB*CT*CD + 255)/256), 256, 0, stream>>>(x, tmx, dxprev, xxx);
    k_gemm<1><<<dim3(3, 32), 256, 0, stream>>>(xxx, maa_w1, nullptr, mbuf, 4096, 160, 768);
    k_mix5<<<dim3(3, 4096), 256, 0, stream>>>(x, dxprev, mbuf, tmw, tmk, tmv, tmr, tmg,
                                              maa_w2, xw, xk, xv, xr, xg);
    k_splitT<<<tg, 256, 0, stream>>>(Wr, BtHi, BtLo, CD, CD);
    k_mgemm<0><<<mg, 256, 0, stream>>>(xr, BtHi, BtLo, rbuf, 4096, CD, CD);
    k_splitT<<<tg, 256, 0, stream>>>(Wk, BtHi, BtLo, CD, CD);
    k_mgemm<0><<<mg, 256, 0, stream>>>(xk, BtHi, BtLo, kbuf, 4096, CD, CD);
    k_splitT<<<tg, 256, 0, stream>>>(Wv, BtHi, BtLo, CD, CD);
    k_mgemm<0><<<mg, 256, 0, stream>>>(xv, BtHi, BtLo, vbuf, 4096, CD, CD);
    k_splitT<<<tg, 256, 0, stream>>>(Wg, BtHi, BtLo, CD, CD);
    k_mgemm<2><<<mg, 256, 0, stream>>>(xg, BtHi, BtLo, gbuf, 4096, CD, CD);
    k_gemm<1><<<dim3(1, 32), 256, 0, stream>>>(xw, decay_w1, nullptr, mbuf, 4096, 64, 768);
    k_gemm<3><<<dim3(12, 32), 256, 0, stream>>>(mbuf, decay_w2, time_decay, wbuf, 4096, 768, 64);

    k_knvx<<<dim3((CB*CH*CT*64)/256), 256, 0, stream>>>(kbuf, vbuf, kn, X);
    k_scan2<<<dim3(CBH), 256, 0, stream>>>(rbuf, kbuf, wbuf, rf, kf, rb, kb);

    for (int bh0 = 0; bh0 < CBH; bh0 += G){
        int Gc = (CBH - bh0 < G) ? (CBH - bh0) : G;
        k_gram<<<dim3(16, 16, Gc), 256, 0, stream>>>(kn, lucid_temp, P, bh0);
        k_potrf0<<<dim3(Gc), 256, 0, stream>>>(P, invL);
        for (int jb = 0; jb < 15; jb++){
            int nt = 15 - jb;
            k_trsm<<<dim3(nt, Gc), 256, 0, stream>>>(P, invL, jb);
            k_syrkpo<<<dim3(nt, nt, Gc), 256, 0, stream>>>(P, invL, jb);
        }
        for (int jb = 0; jb < 16; jb++)
            k_solve<0><<<dim3(16-jb, Gc), 256, 0, stream>>>(P, invL, X, Yb, bh0, jb);
        for (int jb = 15; jb >= 0; jb--)
            k_solve<1><<<dim3(jb+1, Gc), 256, 0, stream>>>(P, invL, X, Yb, bh0, jb);
    }

    k_outer<<<dim3(16, CBH), 256, 0, stream>>>(kf, kb, X, Sf, Sb);
    k_cumsum<<<dim3(CBH), 256, 0, stream>>>(Sf, Sb);
    k_apv2<<<dim3(16, CBH), 256, 0, stream>>>(rf, kf, rb, kb, X, Sf, Sb, ybuf);
    k_gn<<<dim3((CB*CT*CH*64)/256), 256, 0, stream>>>(ybuf, gbuf, lnw, lnb, zbuf);
    k_splitT<<<tg, 256, 0, stream>>>(Wo, BtHi, BtLo, CD, CD);
    k_mgemm<0><<<mg, 256, 0, stream>>>(zbuf, BtHi, BtLo, out, 4096, CD, CD);
}